// Round 2
// baseline (3091.364 us; speedup 1.0000x reference)
//
#include <hip/hip_runtime.h>
#include <hip/hip_bf16.h>

// Problem constants (from reference)
#define B_   2048
#define L_   64
#define H_   20
#define DK_  20
#define D_   300
#define HD_  400
#define F1_  200

// LDS strides (bank-conflict-aware)
#define XS   324   // x row stride (bf16 elems)
#define CS   404   // ctx row stride (bf16 elems)
#define QS   21    // qkv row stride (f32); gcd(21,32)=1 -> conflict-free
#define SS   66    // scores row stride (bf16); dword stride 33 -> conflict-free

__device__ __forceinline__ float b2f(unsigned short u) {
    union { unsigned int i; float f; } v; v.i = ((unsigned int)u) << 16; return v.f;
}
__device__ __forceinline__ unsigned short f2b(float f) {
    union { float f; unsigned int i; } v; v.f = f;
    unsigned int x = v.i;
    return (unsigned short)((x + 0x7fffu + ((x >> 16) & 1u)) >> 16);  // RNE
}
// wave-uniform lane broadcast via v_readlane (VALU, not LDS pipe)
__device__ __forceinline__ float rlane(float v, int l) {
    return __int_as_float(__builtin_amdgcn_readlane(__float_as_int(v), l));
}

__global__ __launch_bounds__(512, 2)
void te_fused(const int* __restrict__ text,
              const float* __restrict__ emb,
              const float* __restrict__ WQ, const float* __restrict__ bQ,
              const float* __restrict__ WK, const float* __restrict__ bK,
              const float* __restrict__ WV, const float* __restrict__ bV,
              const float* __restrict__ W1, const float* __restrict__ b1,
              const float* __restrict__ W2, const float* __restrict__ b2,
              float* __restrict__ out)
{
    __shared__ int            text_s[L_];
    __shared__ unsigned short x_s[L_ * XS];           // 41472 B (bf16 staging of x)
    __shared__ unsigned short ctx_s[L_ * CS];         // 51712 B (bf16 staging of ctx)
    __shared__ float          qkv_s[3 * 2 * L_ * QS]; // 32256 B  [(sel*2+head)*64+row]*21+d
    __shared__ unsigned short sc_s[2 * L_ * SS];      // 16896 B (bf16 exp-scores)
    __shared__ float          aacc_s[L_];
    __shared__ float          alpha_s[L_];
    __shared__ float          inv_asum_s;

    const int b    = blockIdx.x;
    const int t    = threadIdx.x;
    const int lane = t & 63;
    const int wv   = t >> 6;

    if (t < 64)               text_s[t] = text[b * L_ + t];
    if (t >= 64 && t < 128)   aacc_s[t - 64] = 0.f;
    __syncthreads();

    // ---- Phase 0: embedding gather (float4 = 16B coalesced), convert to bf16 ----
    for (int u = t; u < L_ * 75; u += 512) {
        int l  = u / 75;
        int c4 = u - l * 75;
        const float4 w = *(const float4*)(emb + (long)text_s[l] * D_ + c4 * 4);
        ushort4 o;
        o.x = f2b(w.x); o.y = f2b(w.y); o.z = f2b(w.z); o.w = f2b(w.w);
        *(ushort4*)(x_s + l * XS + c4 * 4) = o;
    }
    __syncthreads();

    // ================= head-pair loop =================
    for (int hp = 0; hp < H_ / 2; ++hp) {
        const int h0 = hp * 2;

        // ---- A: QKV projection for heads h0, h0+1 ----
        // output [64 rows x 120 qkv-cols], 4x4 register tiles, 480 active threads
        if (t < 480) {
            const int rt = t & 15, ct = t >> 4;       // ct 0..29
            const int r0 = rt * 4, qc = ct * 4;       // qc 0..116
            const int sel = qc / 40, rem = qc - sel * 40;
            const int hh = rem / 20, cc = rem - hh * 20;
            const float* W    = (sel == 0) ? WQ : (sel == 1) ? WK : WV;
            const float* bias = (sel == 0) ? bQ : (sel == 1) ? bK : bV;
            const int col0 = (h0 + hh) * 20 + cc;
            float acc[4][4];
            #pragma unroll
            for (int j = 0; j < 4; ++j) {
                const float bj = bias[col0 + j];
                acc[0][j] = bj; acc[1][j] = bj; acc[2][j] = bj; acc[3][j] = bj;
            }
            const float* Wp = W + col0;
            for (int c4 = 0; c4 < 75; ++c4) {
                const int d0 = c4 * 4;
                float xv[4][4];
                float4 wvv[4];
                #pragma unroll
                for (int i = 0; i < 4; ++i) {
                    ushort4 xu = *(const ushort4*)(x_s + (r0 + i) * XS + d0);
                    xv[i][0] = b2f(xu.x); xv[i][1] = b2f(xu.y);
                    xv[i][2] = b2f(xu.z); xv[i][3] = b2f(xu.w);
                }
                #pragma unroll
                for (int dd = 0; dd < 4; ++dd)
                    wvv[dd] = *(const float4*)(Wp + (long)(d0 + dd) * HD_);
                #pragma unroll
                for (int dd = 0; dd < 4; ++dd) {
                    #pragma unroll
                    for (int i = 0; i < 4; ++i) {
                        acc[i][0] = fmaf(xv[i][dd], wvv[dd].x, acc[i][0]);
                        acc[i][1] = fmaf(xv[i][dd], wvv[dd].y, acc[i][1]);
                        acc[i][2] = fmaf(xv[i][dd], wvv[dd].z, acc[i][2]);
                        acc[i][3] = fmaf(xv[i][dd], wvv[dd].w, acc[i][3]);
                    }
                }
            }
            #pragma unroll
            for (int i = 0; i < 4; ++i)
                #pragma unroll
                for (int j = 0; j < 4; ++j)
                    qkv_s[((sel * 2 + hh) * L_ + r0 + i) * QS + cc + j] = acc[i][j];
        }
        __syncthreads();

        // ---- B: scores P = exp(q.k / sqrt(20)), stored bf16 ----
        {
            const int j  = lane;
            const int ig = wv & 3;
            const int hh = wv >> 2;
            float qreg[20], kreg[20];
            const float* qrow = &qkv_s[((0 * 2 + hh) * L_ + j) * QS];
            const float* krow = &qkv_s[((1 * 2 + hh) * L_ + j) * QS];
            #pragma unroll
            for (int d = 0; d < 20; ++d) { qreg[d] = qrow[d]; kreg[d] = krow[d]; }
            for (int ii = 0; ii < 16; ++ii) {
                const int i = ig * 16 + ii;
                float s = 0.f;
                #pragma unroll
                for (int d = 0; d < 20; ++d)
                    s = fmaf(rlane(qreg[d], i), kreg[d], s);
                const float p = __expf(s * 0.22360679774997896f);  // 1/sqrt(20)
                sc_s[(hh * L_ + i) * SS + j] = f2b(p);
            }
        }
        __syncthreads();

        // ---- C: ctx[i, col] = (sum_j P[i,j] v[j,dv]) / (rowsum + 1e-8) ----
        {
            const int i    = lane;
            const int dg   = wv;            // 0..7
            const int head = dg >> 2;
            const int dv0  = (dg & 3) * 5;
            float vreg[5];
            #pragma unroll
            for (int m = 0; m < 5; ++m)
                vreg[m] = qkv_s[((2 * 2 + head) * L_ + i) * QS + dv0 + m];
            float acc[5] = {0.f, 0.f, 0.f, 0.f, 0.f};
            float rsum = 0.f;
            const unsigned short* prow = &sc_s[(head * L_ + i) * SS];
            for (int jj = 0; jj < 64; ++jj) {
                const float p = b2f(prow[jj]);
                rsum += p;
                #pragma unroll
                for (int m = 0; m < 5; ++m)
                    acc[m] = fmaf(p, rlane(vreg[m], jj), acc[m]);
            }
            const float inv = 1.f / (rsum + 1e-8f);
            const int col0 = (h0 + head) * 20 + dv0;
            #pragma unroll
            for (int m = 0; m < 5; ++m)
                ctx_s[i * CS + col0 + m] = f2b(acc[m] * inv);
        }
        __syncthreads();   // protects qkv/sc reuse next iteration + final ctx visibility
    }

    // ---- D: e = tanh(ctx@W1+b1); alpha partials += e . W2 (4x4 tiles) ----
    for (int tau = t; tau < 800; tau += 512) {
        const int rt = tau & 15, cm = tau >> 4;   // cm 0..49
        const int r0 = rt * 4, m0 = cm * 4;
        float acc[4][4];
        #pragma unroll
        for (int j = 0; j < 4; ++j) {
            const float bj = b1[m0 + j];
            acc[0][j] = bj; acc[1][j] = bj; acc[2][j] = bj; acc[3][j] = bj;
        }
        for (int c4 = 0; c4 < 100; ++c4) {
            const int c0 = c4 * 4;
            float cv[4][4];
            float4 wv1[4];
            #pragma unroll
            for (int i = 0; i < 4; ++i) {
                ushort4 cu = *(const ushort4*)(ctx_s + (r0 + i) * CS + c0);
                cv[i][0] = b2f(cu.x); cv[i][1] = b2f(cu.y);
                cv[i][2] = b2f(cu.z); cv[i][3] = b2f(cu.w);
            }
            #pragma unroll
            for (int dd = 0; dd < 4; ++dd)
                wv1[dd] = *(const float4*)(W1 + (long)(c0 + dd) * F1_ + m0);
            #pragma unroll
            for (int dd = 0; dd < 4; ++dd) {
                #pragma unroll
                for (int i = 0; i < 4; ++i) {
                    acc[i][0] = fmaf(cv[i][dd], wv1[dd].x, acc[i][0]);
                    acc[i][1] = fmaf(cv[i][dd], wv1[dd].y, acc[i][1]);
                    acc[i][2] = fmaf(cv[i][dd], wv1[dd].z, acc[i][2]);
                    acc[i][3] = fmaf(cv[i][dd], wv1[dd].w, acc[i][3]);
                }
            }
        }
        float w2l[4];
        #pragma unroll
        for (int j = 0; j < 4; ++j) w2l[j] = W2[m0 + j];
        #pragma unroll
        for (int i = 0; i < 4; ++i) {
            float ap = 0.f;
            #pragma unroll
            for (int j = 0; j < 4; ++j)
                ap += tanhf(acc[i][j]) * w2l[j];
            atomicAdd(&aacc_s[r0 + i], ap);
        }
    }
    __syncthreads();

    // ---- alpha = exp(.), normalize ----
    if (t < 64) {
        const float a = __expf(aacc_s[t] + b2[0]);
        alpha_s[t] = a;
        float s = a;
        s += __shfl_xor(s, 32, 64); s += __shfl_xor(s, 16, 64);
        s += __shfl_xor(s, 8, 64);  s += __shfl_xor(s, 4, 64);
        s += __shfl_xor(s, 2, 64);  s += __shfl_xor(s, 1, 64);
        if (t == 0) inv_asum_s = 1.f / (s + 1e-8f);
    }
    __syncthreads();

    // ---- E: out[c] = sum_l ctx[l,c] * alpha[l] * inv_sum ----
    if (t < HD_) {
        float a = 0.f;
        for (int l = 0; l < 64; ++l)
            a = fmaf(b2f(ctx_s[l * CS + t]), alpha_s[l], a);
        out[(long)b * HD_ + t] = a * inv_asum_s;
    }
}

extern "C" void kernel_launch(void* const* d_in, const int* in_sizes, int n_in,
                              void* d_out, int out_size, void* d_ws, size_t ws_size,
                              hipStream_t stream) {
    const int*   text = (const int*)d_in[0];
    const float* emb  = (const float*)d_in[1];
    const float* WQ   = (const float*)d_in[2];
    const float* bQ   = (const float*)d_in[3];
    const float* WK   = (const float*)d_in[4];
    const float* bK   = (const float*)d_in[5];
    const float* WV   = (const float*)d_in[6];
    const float* bV   = (const float*)d_in[7];
    const float* W1   = (const float*)d_in[8];
    const float* b1   = (const float*)d_in[9];
    const float* W2   = (const float*)d_in[10];
    const float* b2   = (const float*)d_in[11];
    float*       out  = (float*)d_out;

    te_fused<<<B_, 512, 0, stream>>>(text, emb, WQ, bQ, WK, bK, WV, bV,
                                     W1, b1, W2, b2, out);
}

// Round 3
// 572.017 us; speedup vs baseline: 5.4043x; 5.4043x over previous
//
#include <hip/hip_runtime.h>
#include <hip/hip_bf16.h>

#define B_   2048
#define L_   64
#define H_   20
#define DK_  20
#define D_   300
#define HD_  400
#define F1_  200

typedef __attribute__((ext_vector_type(8))) short short8;
typedef __attribute__((ext_vector_type(4))) float f32x4;

// ws layout: [wqkv_pack: 5*10*16 tiles * 1024B = 819200][w1_pack: 13*13 tiles * 1024B = 173056]
#define WQKV_TILES   800            // hg(5) * kt(10) * nt(16)
#define W1_TILES     169            // kt(13) * nt(13)
#define W1_OFF_U16   409600         // 819200 B / 2
#define WS_NEEDED    992256

__device__ __forceinline__ float b2f(unsigned short u) {
    union { unsigned int i; float f; } v; v.i = ((unsigned int)u) << 16; return v.f;
}
__device__ __forceinline__ unsigned short f2b(float f) {
    union { float f; unsigned int i; } v; v.f = f;
    unsigned int x = v.i;
    return (unsigned short)((x + 0x7fffu + ((x >> 16) & 1u)) >> 16);  // RNE
}
__device__ __forceinline__ float rlane(float v, int l) {
    return __int_as_float(__builtin_amdgcn_readlane(__float_as_int(v), l));
}

// ============================ weight pre-pack ============================
// Packs W{Q,K,V} -> bf16 MFMA-B fragments [hg][kt][nt][lane][8] and W1 likewise.
// B-frag mapping (16x16x32): lane holds B[k = kt*32 + (lane>>4)*8 + j][n = nt*16 + (lane&15)]
__global__ void pack_weights(const float* __restrict__ WQ, const float* __restrict__ WK,
                             const float* __restrict__ WV, const float* __restrict__ W1,
                             unsigned short* __restrict__ wsp)
{
    const int tid  = blockIdx.x * 256 + threadIdx.x;
    const int frag = tid >> 6, l = tid & 63;
    if (frag >= WQKV_TILES + W1_TILES) return;
    const int octet = l >> 4, lo = l & 15;
    unsigned short v[8];
    if (frag < WQKV_TILES) {
        const int hg = frag / 160, r = frag % 160, kt = r / 16, nt = r % 16;
        const int nl = nt * 16 + lo;                  // n_local in [0,256)
        const int sel = (nl < 240) ? nl / 80 : 0;
        const int within = nl % 80;
        const int h2 = within / 20, d = within % 20;
        const int col = (hg * 4 + h2) * 20 + d;
        const float* W = (sel == 0) ? WQ : (sel == 1) ? WK : WV;
        #pragma unroll
        for (int j = 0; j < 8; ++j) {
            const int k = kt * 32 + octet * 8 + j;
            const float f = (nl < 240 && k < 300) ? W[k * 400 + col] : 0.f;
            v[j] = f2b(f);
        }
    } else {
        const int f2 = frag - WQKV_TILES, kt = f2 / 13, nt = f2 % 13;
        const int n = nt * 16 + lo;
        #pragma unroll
        for (int j = 0; j < 8; ++j) {
            const int k = kt * 32 + octet * 8 + j;
            const float f = (n < 200 && k < 400) ? W1[k * 200 + n] : 0.f;
            v[j] = f2b(f);
        }
    }
    unsigned short* dst = wsp + (long)frag * 512 + l * 8;
    *(ushort4*)(dst)     = make_ushort4(v[0], v[1], v[2], v[3]);
    *(ushort4*)(dst + 4) = make_ushort4(v[4], v[5], v[6], v[7]);
}

// ============================ fused main kernel ============================
__global__ __launch_bounds__(512, 2)
void te_mfma(const int* __restrict__ text,
             const float* __restrict__ emb,
             const float* __restrict__ bQ, const float* __restrict__ bK,
             const float* __restrict__ bV, const float* __restrict__ b1,
             const float* __restrict__ W2, const float* __restrict__ b2,
             const unsigned short* __restrict__ wsp,
             float* __restrict__ out)
{
    // A-layout x: [mt(4)][kt(10)][lane][8]  (token = mt*16 + lane&15, k = kt*32+(lane>>4)*8+j)
    __shared__ unsigned short x_pack[4 * 10 * 64 * 8];      // 40960 B
    // A-layout ctx: [mt(4)][kt(13)][lane][8] (col = kt*32+(lane>>4)*8+j)
    __shared__ unsigned short ctxA[4 * 13 * 64 * 8];        // 53248 B
    // transient: qA [h][mt] @0 (8192 us) + kB [h][jt] @8192 ; overlaid by pA [h][mt][kt(2)]
    __shared__ unsigned short trans[16384];                 // 32768 B
    // vB: [h][kt(2)][dnt(2)][lane][8]  (B-frag for PV; d==20 column = 1.0 -> rowsum)
    __shared__ unsigned short vB[8192];                     // 16384 B
    __shared__ float rsum_s[4 * 64];
    __shared__ float bqkv_s[3 * 400];
    __shared__ float b1_s[208];
    __shared__ float w2_s[208];
    __shared__ int   text_s[64];
    __shared__ float aacc_s[64], alpha_s[64];
    __shared__ float inv_asum_s;

    const int b = blockIdx.x;
    const int t = threadIdx.x;
    const int l = t & 63;
    const int w = t >> 6;

    // ---- block init ----
    {
        unsigned int* xz = (unsigned int*)x_pack;
        for (int i = t; i < 10240; i += 512) xz[i] = 0u;
        unsigned int* cz = (unsigned int*)ctxA;
        for (int i = t; i < 13312; i += 512) cz[i] = 0u;
        for (int i = t; i < 1200; i += 512)
            bqkv_s[i] = (i < 400) ? bQ[i] : (i < 800) ? bK[i - 400] : bV[i - 800];
        if (t < 208) { b1_s[t] = (t < 200) ? b1[t] : 0.f; w2_s[t] = (t < 200) ? W2[t] : 0.f; }
        if (t >= 208 && t < 272) aacc_s[t - 208] = 0.f;
        if (t >= 272 && t < 336) text_s[t - 272] = text[b * L_ + (t - 272)];
    }
    __syncthreads();

    // ---- embedding gather -> x_pack (bf16 A-layout) ----
    for (int u = t; u < 64 * 75; u += 512) {
        const int r = u / 75, c4 = u - r * 75, k = c4 * 4;
        const float4 f = *(const float4*)(emb + (long)text_s[r] * D_ + k);
        const int mt = r >> 4, kt = k >> 5;
        const int ld = (r & 15) + ((k & 31) >> 3) * 16;
        const int off = ((mt * 10 + kt) * 64 + ld) * 8 + (k & 7);
        ushort4 o; o.x = f2b(f.x); o.y = f2b(f.y); o.z = f2b(f.z); o.w = f2b(f.w);
        *(ushort4*)(x_pack + off) = o;
    }
    __syncthreads();

    // ================= head-group loop (4 heads per group) =================
    for (int hg = 0; hg < 5; ++hg) {
        // ---- init transient: zero qA/kB; vB zeros + ones column (d==20) ----
        {
            unsigned int* tz = (unsigned int*)trans;
            for (int i = t; i < 8192; i += 512) tz[i] = 0u;
            unsigned int* vz = (unsigned int*)vB;
            for (int i = t; i < 4096; i += 512) {
                const int lane_v = (i >> 2) & 63;
                const int dnt    = (i >> 8) & 1;
                vz[i] = (dnt == 1 && (lane_v & 15) == 4) ? 0x3F803F80u : 0u;
            }
        }
        __syncthreads();

        // ---- Phase A: qkv slice [64 x 240(pad 256)] via MFMA ----
        f32x4 accA[2][4];
        #pragma unroll
        for (int p = 0; p < 2; ++p)
            #pragma unroll
            for (int mt = 0; mt < 4; ++mt) accA[p][mt] = (f32x4){0.f, 0.f, 0.f, 0.f};
        {
            const int nt0 = 2 * w, nt1 = 2 * w + 1;
            for (int kt = 0; kt < 10; ++kt) {
                short8 a[4];
                #pragma unroll
                for (int mt = 0; mt < 4; ++mt)
                    a[mt] = *(const short8*)(x_pack + ((mt * 10 + kt) * 64 + l) * 8);
                const short8 b0 = *(const short8*)(wsp + ((long)(hg * 160 + kt * 16 + nt0) * 512) + l * 8);
                const short8 b1f = *(const short8*)(wsp + ((long)(hg * 160 + kt * 16 + nt1) * 512) + l * 8);
                #pragma unroll
                for (int mt = 0; mt < 4; ++mt) {
                    accA[0][mt] = __builtin_amdgcn_mfma_f32_16x16x32_bf16(a[mt], b0,  accA[0][mt], 0, 0, 0);
                    accA[1][mt] = __builtin_amdgcn_mfma_f32_16x16x32_bf16(a[mt], b1f, accA[1][mt], 0, 0, 0);
                }
            }
        }
        // ---- A epilogue: +bias, cvt, scatter into qA/kB/vB layouts ----
        #pragma unroll
        for (int p = 0; p < 2; ++p) {
            const int nl = (2 * w + p) * 16 + (l & 15);
            if (nl < 240) {
                const int sel = nl / 80, within = nl % 80;
                const int h2 = within / 20, d = within % 20;
                const float bias = bqkv_s[sel * 400 + (hg * 4 + h2) * 20 + d];
                #pragma unroll
                for (int mt = 0; mt < 4; ++mt)
                    #pragma unroll
                    for (int ii = 0; ii < 4; ++ii) {
                        const int tok = mt * 16 + (l >> 4) * 4 + ii;
                        const unsigned short us = f2b(accA[p][mt][ii] + bias);
                        if (sel == 0) {
                            const int ld = (tok & 15) + (d >> 3) * 16;
                            trans[((h2 * 4 + mt) * 64 + ld) * 8 + (d & 7)] = us;
                        } else if (sel == 1) {
                            const int ld = (tok & 15) + (d >> 3) * 16;
                            trans[8192 + ((h2 * 4 + mt) * 64 + ld) * 8 + (d & 7)] = us;
                        } else {
                            const int ktv = tok >> 5;
                            const int ld  = (d & 15) + ((tok & 31) >> 3) * 16;
                            vB[(((h2 * 2 + ktv) * 2 + (d >> 4)) * 64 + ld) * 8 + (tok & 7)] = us;
                        }
                    }
            }
        }
        __syncthreads();

        // ---- Phase B: S = Q@K^T (one kt, d padded to 32), exp, -> pA ----
        const int h  = w >> 1;
        const int jh = w & 1;
        f32x4 accS[2][4];
        #pragma unroll
        for (int p = 0; p < 2; ++p)
            #pragma unroll
            for (int mt = 0; mt < 4; ++mt) accS[p][mt] = (f32x4){0.f, 0.f, 0.f, 0.f};
        {
            short8 qa[4], kb[2];
            #pragma unroll
            for (int mt = 0; mt < 4; ++mt)
                qa[mt] = *(const short8*)(trans + ((h * 4 + mt) * 64 + l) * 8);
            #pragma unroll
            for (int p = 0; p < 2; ++p)
                kb[p] = *(const short8*)(trans + 8192 + ((h * 4 + jh * 2 + p) * 64 + l) * 8);
            #pragma unroll
            for (int p = 0; p < 2; ++p)
                #pragma unroll
                for (int mt = 0; mt < 4; ++mt)
                    accS[p][mt] = __builtin_amdgcn_mfma_f32_16x16x32_bf16(qa[mt], kb[p], accS[p][mt], 0, 0, 0);
        }
        __syncthreads();   // everyone done reading qA/kB before pA overlays
        #pragma unroll
        for (int p = 0; p < 2; ++p) {
            const int jtok = (jh * 2 + p) * 16 + (l & 15);
            const int ktp = jtok >> 5;
            #pragma unroll
            for (int mt = 0; mt < 4; ++mt)
                #pragma unroll
                for (int ii = 0; ii < 4; ++ii) {
                    const int itok = mt * 16 + (l >> 4) * 4 + ii;
                    const float pv = __expf(accS[p][mt][ii] * 0.22360679774997896f);
                    const int ld = (itok & 15) + ((jtok & 31) >> 3) * 16;
                    trans[(((h * 4 + mt) * 2 + ktp) * 64 + ld) * 8 + (jtok & 7)] = f2b(pv);
                }
        }
        __syncthreads();

        // ---- Phase C: PV (+rowsum via ones column), normalize -> ctxA ----
        const int dnt = w & 1;
        f32x4 accC[4];
        #pragma unroll
        for (int mt = 0; mt < 4; ++mt) accC[mt] = (f32x4){0.f, 0.f, 0.f, 0.f};
        #pragma unroll
        for (int ktc = 0; ktc < 2; ++ktc) {
            const short8 vb = *(const short8*)(vB + (((h * 2 + ktc) * 2 + dnt) * 64 + l) * 8);
            #pragma unroll
            for (int mt = 0; mt < 4; ++mt) {
                const short8 pa = *(const short8*)(trans + (((h * 4 + mt) * 2 + ktc) * 64 + l) * 8);
                accC[mt] = __builtin_amdgcn_mfma_f32_16x16x32_bf16(pa, vb, accC[mt], 0, 0, 0);
            }
        }
        if (dnt == 1 && (l & 15) == 4) {
            #pragma unroll
            for (int mt = 0; mt < 4; ++mt)
                #pragma unroll
                for (int ii = 0; ii < 4; ++ii)
                    rsum_s[h * 64 + mt * 16 + (l >> 4) * 4 + ii] = accC[mt][ii];
        }
        __syncthreads();
        {
            const int dloc = dnt * 16 + (l & 15);
            if (dloc < 20) {
                const int col = (hg * 4 + h) * 20 + dloc;
                const int ktx = col >> 5;
                const int ldx = ((col & 31) >> 3) * 16;
                #pragma unroll
                for (int mt = 0; mt < 4; ++mt)
                    #pragma unroll
                    for (int ii = 0; ii < 4; ++ii) {
                        const int tok = mt * 16 + (l >> 4) * 4 + ii;
                        const float inv = 1.f / (rsum_s[h * 64 + tok] + 1e-8f);
                        ctxA[((mt * 13 + ktx) * 64 + (tok & 15) + ldx) * 8 + (col & 7)] =
                            f2b(accC[mt][ii] * inv);
                    }
            }
        }
        __syncthreads();
    }

    // ---- Phase D: e = tanh(ctx@W1+b1); alpha_logit = e@W2 ----
    {
        const int nta = w, ntb = w + 8;   // ntb valid if < 13
        f32x4 accD[2][4];
        #pragma unroll
        for (int g = 0; g < 2; ++g)
            #pragma unroll
            for (int mt = 0; mt < 4; ++mt) accD[g][mt] = (f32x4){0.f, 0.f, 0.f, 0.f};
        for (int kt = 0; kt < 13; ++kt) {
            short8 ca[4];
            #pragma unroll
            for (int mt = 0; mt < 4; ++mt)
                ca[mt] = *(const short8*)(ctxA + ((mt * 13 + kt) * 64 + l) * 8);
            const short8 wb0 = *(const short8*)(wsp + W1_OFF_U16 + ((long)(kt * 13 + nta) * 512) + l * 8);
            #pragma unroll
            for (int mt = 0; mt < 4; ++mt)
                accD[0][mt] = __builtin_amdgcn_mfma_f32_16x16x32_bf16(ca[mt], wb0, accD[0][mt], 0, 0, 0);
            if (ntb < 13) {
                const short8 wb1 = *(const short8*)(wsp + W1_OFF_U16 + ((long)(kt * 13 + ntb) * 512) + l * 8);
                #pragma unroll
                for (int mt = 0; mt < 4; ++mt)
                    accD[1][mt] = __builtin_amdgcn_mfma_f32_16x16x32_bf16(ca[mt], wb1, accD[1][mt], 0, 0, 0);
            }
        }
        float part[4][4];
        #pragma unroll
        for (int mt = 0; mt < 4; ++mt)
            #pragma unroll
            for (int ii = 0; ii < 4; ++ii) part[mt][ii] = 0.f;
        #pragma unroll
        for (int g = 0; g < 2; ++g) {
            const int ntv = (g == 0) ? nta : ntb;
            if (ntv < 13) {
                const int colb = ntv * 16 + (l & 15);
                const float b1v = b1_s[colb], w2v = w2_s[colb];
                #pragma unroll
                for (int mt = 0; mt < 4; ++mt)
                    #pragma unroll
                    for (int ii = 0; ii < 4; ++ii) {
                        const float x = accD[g][mt][ii] + b1v;
                        const float ex = __expf(2.f * x);
                        part[mt][ii] += ((ex - 1.f) / (ex + 1.f)) * w2v;
                    }
            }
        }
        #pragma unroll
        for (int mt = 0; mt < 4; ++mt)
            #pragma unroll
            for (int ii = 0; ii < 4; ++ii) {
                float v = part[mt][ii];
                v += __shfl_xor(v, 1, 64); v += __shfl_xor(v, 2, 64);
                v += __shfl_xor(v, 4, 64); v += __shfl_xor(v, 8, 64);
                if ((l & 15) == 0)
                    atomicAdd(&aacc_s[mt * 16 + (l >> 4) * 4 + ii], v);
            }
    }
    __syncthreads();

    // ---- alpha = exp(.) / (sum + 1e-8) ----
    if (t < 64) {
        const float a = __expf(aacc_s[t] + b2[0]);
        alpha_s[t] = a;
        float s = a;
        s += __shfl_xor(s, 32, 64); s += __shfl_xor(s, 16, 64);
        s += __shfl_xor(s, 8, 64);  s += __shfl_xor(s, 4, 64);
        s += __shfl_xor(s, 2, 64);  s += __shfl_xor(s, 1, 64);
        if (t == 0) inv_asum_s = 1.f / (s + 1e-8f);
    }
    __syncthreads();

    // ---- output: out[c] = sum_tok ctx[tok][c] * alpha[tok] * inv ----
    if (t < HD_) {
        const int c = t;
        const int ktx = c >> 5, ldo = ((c & 31) >> 3) * 16, el = c & 7;
        float a = 0.f;
        for (int tok = 0; tok < 64; ++tok) {
            const unsigned short us =
                ctxA[(((tok >> 4) * 13 + ktx) * 64 + (tok & 15) + ldo) * 8 + el];
            a = fmaf(b2f(us), alpha_s[tok], a);
        }
        out[(long)b * HD_ + c] = a * inv_asum_s;
    }
}

// ============================ fallback (R2, no ws) ============================
#define XS   324
#define CS   404
#define QS   21
#define SS   66

__global__ __launch_bounds__(512, 2)
void te_fused_fb(const int* __restrict__ text, const float* __restrict__ emb,
                 const float* __restrict__ WQ, const float* __restrict__ bQ,
                 const float* __restrict__ WK, const float* __restrict__ bK,
                 const float* __restrict__ WV, const float* __restrict__ bV,
                 const float* __restrict__ W1, const float* __restrict__ b1,
                 const float* __restrict__ W2, const float* __restrict__ b2,
                 float* __restrict__ out)
{
    __shared__ int            text_s[L_];
    __shared__ unsigned short x_s[L_ * XS];
    __shared__ unsigned short ctx_s[L_ * CS];
    __shared__ float          qkv_s[3 * 2 * L_ * QS];
    __shared__ unsigned short sc_s[2 * L_ * SS];
    __shared__ float          aacc_s[L_], alpha_s[L_];
    __shared__ float          inv_asum_s;

    const int b = blockIdx.x, t = threadIdx.x, lane = t & 63, wv = t >> 6;
    if (t < 64) text_s[t] = text[b * L_ + t];
    if (t >= 64 && t < 128) aacc_s[t - 64] = 0.f;
    __syncthreads();
    for (int u = t; u < L_ * 75; u += 512) {
        int l = u / 75, c4 = u - l * 75;
        const float4 f = *(const float4*)(emb + (long)text_s[l] * D_ + c4 * 4);
        ushort4 o; o.x = f2b(f.x); o.y = f2b(f.y); o.z = f2b(f.z); o.w = f2b(f.w);
        *(ushort4*)(x_s + l * XS + c4 * 4) = o;
    }
    __syncthreads();
    for (int hp = 0; hp < H_ / 2; ++hp) {
        const int h0 = hp * 2;
        if (t < 480) {
            const int rt = t & 15, ct = t >> 4, r0 = rt * 4, qc = ct * 4;
            const int sel = qc / 40, rem = qc - sel * 40, hh = rem / 20, cc = rem - hh * 20;
            const float* W = (sel == 0) ? WQ : (sel == 1) ? WK : WV;
            const float* bias = (sel == 0) ? bQ : (sel == 1) ? bK : bV;
            const int col0 = (h0 + hh) * 20 + cc;
            float acc[4][4];
            #pragma unroll
            for (int j = 0; j < 4; ++j) {
                const float bj = bias[col0 + j];
                acc[0][j] = bj; acc[1][j] = bj; acc[2][j] = bj; acc[3][j] = bj;
            }
            const float* Wp = W + col0;
            for (int c4 = 0; c4 < 75; ++c4) {
                const int d0 = c4 * 4;
                float xv[4][4]; float4 wvv[4];
                #pragma unroll
                for (int i = 0; i < 4; ++i) {
                    ushort4 xu = *(const ushort4*)(x_s + (r0 + i) * XS + d0);
                    xv[i][0] = b2f(xu.x); xv[i][1] = b2f(xu.y);
                    xv[i][2] = b2f(xu.z); xv[i][3] = b2f(xu.w);
                }
                #pragma unroll
                for (int dd = 0; dd < 4; ++dd)
                    wvv[dd] = *(const float4*)(Wp + (long)(d0 + dd) * HD_);
                #pragma unroll
                for (int dd = 0; dd < 4; ++dd)
                    #pragma unroll
                    for (int i = 0; i < 4; ++i) {
                        acc[i][0] = fmaf(xv[i][dd], wvv[dd].x, acc[i][0]);
                        acc[i][1] = fmaf(xv[i][dd], wvv[dd].y, acc[i][1]);
                        acc[i][2] = fmaf(xv[i][dd], wvv[dd].z, acc[i][2]);
                        acc[i][3] = fmaf(xv[i][dd], wvv[dd].w, acc[i][3]);
                    }
            }
            #pragma unroll
            for (int i = 0; i < 4; ++i)
                #pragma unroll
                for (int j = 0; j < 4; ++j)
                    qkv_s[((sel * 2 + hh) * L_ + r0 + i) * QS + cc + j] = acc[i][j];
        }
        __syncthreads();
        {
            const int j = lane, ig = wv & 3, hh = wv >> 2;
            float qreg[20], kreg[20];
            const float* qrow = &qkv_s[((0 * 2 + hh) * L_ + j) * QS];
            const float* krow = &qkv_s[((1 * 2 + hh) * L_ + j) * QS];
            #pragma unroll
            for (int d = 0; d < 20; ++d) { qreg[d] = qrow[d]; kreg[d] = krow[d]; }
            for (int ii = 0; ii < 16; ++ii) {
                const int i = ig * 16 + ii;
                float s = 0.f;
                #pragma unroll
                for (int d = 0; d < 20; ++d) s = fmaf(rlane(qreg[d], i), kreg[d], s);
                sc_s[(hh * L_ + i) * SS + j] = f2b(__expf(s * 0.22360679774997896f));
            }
        }
        __syncthreads();
        {
            const int i = lane, dg = wv, head = dg >> 2, dv0 = (dg & 3) * 5;
            float vreg[5];
            #pragma unroll
            for (int m = 0; m < 5; ++m)
                vreg[m] = qkv_s[((2 * 2 + head) * L_ + i) * QS + dv0 + m];
            float acc[5] = {0.f, 0.f, 0.f, 0.f, 0.f};
            float rsum = 0.f;
            const unsigned short* prow = &sc_s[(head * L_ + i) * SS];
            for (int jj = 0; jj < 64; ++jj) {
                const float p = b2f(prow[jj]);
                rsum += p;
                #pragma unroll
                for (int m = 0; m < 5; ++m) acc[m] = fmaf(p, rlane(vreg[m], jj), acc[m]);
            }
            const float inv = 1.f / (rsum + 1e-8f);
            const int col0 = (h0 + head) * 20 + dv0;
            #pragma unroll
            for (int m = 0; m < 5; ++m) ctx_s[i * CS + col0 + m] = f2b(acc[m] * inv);
        }
        __syncthreads();
    }
    for (int tau = t; tau < 800; tau += 512) {
        const int rt = tau & 15, cm = tau >> 4, r0 = rt * 4, m0 = cm * 4;
        float acc[4][4];
        #pragma unroll
        for (int j = 0; j < 4; ++j) {
            const float bj = b1[m0 + j];
            acc[0][j] = bj; acc[1][j] = bj; acc[2][j] = bj; acc[3][j] = bj;
        }
        for (int c4 = 0; c4 < 100; ++c4) {
            const int c0 = c4 * 4;
            float cv[4][4]; float4 wv1[4];
            #pragma unroll
            for (int i = 0; i < 4; ++i) {
                ushort4 cu = *(const ushort4*)(ctx_s + (r0 + i) * CS + c0);
                cv[i][0] = b2f(cu.x); cv[i][1] = b2f(cu.y);
                cv[i][2] = b2f(cu.z); cv[i][3] = b2f(cu.w);
            }
            #pragma unroll
            for (int dd = 0; dd < 4; ++dd)
                wv1[dd] = *(const float4*)(W1 + (long)(c0 + dd) * F1_ + m0);
            #pragma unroll
            for (int dd = 0; dd < 4; ++dd)
                #pragma unroll
                for (int i = 0; i < 4; ++i) {
                    acc[i][0] = fmaf(cv[i][dd], wv1[dd].x, acc[i][0]);
                    acc[i][1] = fmaf(cv[i][dd], wv1[dd].y, acc[i][1]);
                    acc[i][2] = fmaf(cv[i][dd], wv1[dd].z, acc[i][2]);
                    acc[i][3] = fmaf(cv[i][dd], wv1[dd].w, acc[i][3]);
                }
        }
        float w2l[4];
        #pragma unroll
        for (int j = 0; j < 4; ++j) w2l[j] = W2[m0 + j];
        #pragma unroll
        for (int i = 0; i < 4; ++i) {
            float ap = 0.f;
            #pragma unroll
            for (int j = 0; j < 4; ++j) ap += tanhf(acc[i][j]) * w2l[j];
            atomicAdd(&aacc_s[r0 + i], ap);
        }
    }
    __syncthreads();
    if (t < 64) {
        const float a = __expf(aacc_s[t] + b2[0]);
        alpha_s[t] = a;
        float s = a;
        s += __shfl_xor(s, 32, 64); s += __shfl_xor(s, 16, 64);
        s += __shfl_xor(s, 8, 64);  s += __shfl_xor(s, 4, 64);
        s += __shfl_xor(s, 2, 64);  s += __shfl_xor(s, 1, 64);
        if (t == 0) inv_asum_s = 1.f / (s + 1e-8f);
    }
    __syncthreads();
    if (t < HD_) {
        float a = 0.f;
        for (int l2 = 0; l2 < 64; ++l2)
            a = fmaf(b2f(ctx_s[l2 * CS + t]), alpha_s[l2], a);
        out[(long)b * HD_ + t] = a * inv_asum_s;
    }
}

extern "C" void kernel_launch(void* const* d_in, const int* in_sizes, int n_in,
                              void* d_out, int out_size, void* d_ws, size_t ws_size,
                              hipStream_t stream) {
    const int*   text = (const int*)d_in[0];
    const float* emb  = (const float*)d_in[1];
    const float* WQ   = (const float*)d_in[2];
    const float* bQ   = (const float*)d_in[3];
    const float* WK   = (const float*)d_in[4];
    const float* bK   = (const float*)d_in[5];
    const float* WV   = (const float*)d_in[6];
    const float* bV   = (const float*)d_in[7];
    const float* W1   = (const float*)d_in[8];
    const float* b1   = (const float*)d_in[9];
    const float* W2   = (const float*)d_in[10];
    const float* b2   = (const float*)d_in[11];
    float*       out  = (float*)d_out;

    if (ws_size >= (size_t)WS_NEEDED) {
        unsigned short* wsp = (unsigned short*)d_ws;
        const int total_frag_threads = (WQKV_TILES + W1_TILES) * 64;
        pack_weights<<<(total_frag_threads + 255) / 256, 256, 0, stream>>>(WQ, WK, WV, W1, wsp);
        te_mfma<<<B_, 512, 0, stream>>>(text, emb, bQ, bK, bV, b1, W2, b2, wsp, out);
    } else {
        te_fused_fb<<<B_, 512, 0, stream>>>(text, emb, WQ, bQ, WK, bK, WV, bV,
                                            W1, b1, W2, b2, out);
    }
}

// Round 4
// 422.802 us; speedup vs baseline: 7.3116x; 1.3529x over previous
//
#include <hip/hip_runtime.h>
#include <hip/hip_bf16.h>

#define B_   2048
#define L_   64
#define H_   20
#define DK_  20
#define D_   300
#define HD_  400
#define F1_  200

typedef __attribute__((ext_vector_type(8))) short short8;
typedef __attribute__((ext_vector_type(4))) float f32x4;

// ws layout: [wqkv_pack: 5*10*16 tiles * 1024B = 819200][w1_pack: 13*13 tiles * 1024B = 173056]
#define WQKV_TILES   800            // hg(5) * kt(10) * nt(16)
#define W1_TILES     169            // kt(13) * nt(13)
#define W1_OFF_U16   409600         // 819200 B / 2
#define WS_NEEDED    992256

__device__ __forceinline__ float b2f(unsigned short u) {
    union { unsigned int i; float f; } v; v.i = ((unsigned int)u) << 16; return v.f;
}
__device__ __forceinline__ unsigned short f2b(float f) {
    union { float f; unsigned int i; } v; v.f = f;
    unsigned int x = v.i;
    return (unsigned short)((x + 0x7fffu + ((x >> 16) & 1u)) >> 16);  // RNE
}
__device__ __forceinline__ float rlane(float v, int l) {
    return __int_as_float(__builtin_amdgcn_readlane(__float_as_int(v), l));
}

// ============================ weight pre-pack ============================
// B-frag mapping (16x16x32): lane holds B[k = kt*32 + (lane>>4)*8 + j][n = nt*16 + (lane&15)]
__global__ void pack_weights(const float* __restrict__ WQ, const float* __restrict__ WK,
                             const float* __restrict__ WV, const float* __restrict__ W1,
                             unsigned short* __restrict__ wsp)
{
    const int tid  = blockIdx.x * 256 + threadIdx.x;
    const int frag = tid >> 6, l = tid & 63;
    if (frag >= WQKV_TILES + W1_TILES) return;
    const int octet = l >> 4, lo = l & 15;
    unsigned short v[8];
    if (frag < WQKV_TILES) {
        const int hg = frag / 160, r = frag % 160, kt = r / 16, nt = r % 16;
        const int nl = nt * 16 + lo;                  // n_local in [0,256)
        const int sel = (nl < 240) ? nl / 80 : 0;
        const int within = nl % 80;
        const int h2 = within / 20, d = within % 20;
        const int col = (hg * 4 + h2) * 20 + d;
        const float* W = (sel == 0) ? WQ : (sel == 1) ? WK : WV;
        #pragma unroll
        for (int j = 0; j < 8; ++j) {
            const int k = kt * 32 + octet * 8 + j;
            const float f = (nl < 240 && k < 300) ? W[k * 400 + col] : 0.f;
            v[j] = f2b(f);
        }
    } else {
        const int f2 = frag - WQKV_TILES, kt = f2 / 13, nt = f2 % 13;
        const int n = nt * 16 + lo;
        #pragma unroll
        for (int j = 0; j < 8; ++j) {
            const int k = kt * 32 + octet * 8 + j;
            const float f = (n < 200 && k < 400) ? W1[k * 200 + n] : 0.f;
            v[j] = f2b(f);
        }
    }
    unsigned short* dst = wsp + (long)frag * 512 + l * 8;
    *(ushort4*)(dst)     = make_ushort4(v[0], v[1], v[2], v[3]);
    *(ushort4*)(dst + 4) = make_ushort4(v[4], v[5], v[6], v[7]);
}

// ============================ fused main kernel (1024 thr = 16 waves) ============================
__global__ __launch_bounds__(1024, 4)
void te_mfma(const int* __restrict__ text,
             const float* __restrict__ emb,
             const float* __restrict__ bQ, const float* __restrict__ bK,
             const float* __restrict__ bV, const float* __restrict__ b1,
             const float* __restrict__ W2, const float* __restrict__ b2,
             const unsigned short* __restrict__ wsp,
             float* __restrict__ out)
{
    __shared__ unsigned short x_pack[4 * 10 * 64 * 8];      // 40960 B  A-layout x
    __shared__ unsigned short ctxA[4 * 13 * 64 * 8];        // 53248 B  A-layout ctx
    // trans: qA [h][mt] @0 (8192 us) + kB [h][jt] @8192 ; overlaid by pA [h][mt][kt(2)]
    __shared__ unsigned short trans[16384];                 // 32768 B
    // vB: [h][ktv(2)][dnt(2)][lane][8]; d==20 column = 1.0 -> rowsum; pads never clobbered
    __shared__ unsigned short vB[8192];                     // 16384 B
    __shared__ float rsum_s[4 * 64];
    __shared__ float bqkv_s[3 * 400];
    __shared__ float b1_s[208];
    __shared__ float w2_s[208];
    __shared__ int   text_s[64];
    __shared__ float aacc_s[64], alpha_s[64];
    __shared__ float inv_asum_s;

    const int b = blockIdx.x;
    const int t = threadIdx.x;
    const int l = t & 63;
    const int w = t >> 6;          // 0..15

    // ---- block init ----
    {
        unsigned int* xz = (unsigned int*)x_pack;
        for (int i = t; i < 10240; i += 1024) xz[i] = 0u;
        unsigned int* cz = (unsigned int*)ctxA;
        for (int i = t; i < 13312; i += 1024) cz[i] = 0u;
        unsigned int* tz = (unsigned int*)trans;
        for (int i = t; i < 8192; i += 1024) tz[i] = 0u;
        unsigned int* vz = (unsigned int*)vB;
        for (int i = t; i < 4096; i += 1024) {
            const int lane_v = (i >> 2) & 63;
            const int dnt    = (i >> 8) & 1;
            vz[i] = (dnt == 1 && (lane_v & 15) == 4) ? 0x3F803F80u : 0u;
        }
        for (int i = t; i < 1200; i += 1024)
            bqkv_s[i] = (i < 400) ? bQ[i] : (i < 800) ? bK[i - 400] : bV[i - 800];
        if (t < 208) { b1_s[t] = (t < 200) ? b1[t] : 0.f; w2_s[t] = (t < 200) ? W2[t] : 0.f; }
        if (t >= 208 && t < 272) aacc_s[t - 208] = 0.f;
        if (t >= 272 && t < 336) text_s[t - 272] = text[b * L_ + (t - 272)];
    }
    __syncthreads();

    // ---- embedding gather -> x_pack (bf16 A-layout) ----
    for (int u = t; u < 64 * 75; u += 1024) {
        const int r = u / 75, c4 = u - r * 75, k = c4 * 4;
        const float4 f = *(const float4*)(emb + (long)text_s[r] * D_ + k);
        const int mt = r >> 4, kt = k >> 5;
        const int ld = (r & 15) + ((k & 31) >> 3) * 16;
        const int off = ((mt * 10 + kt) * 64 + ld) * 8 + (k & 7);
        ushort4 o; o.x = f2b(f.x); o.y = f2b(f.y); o.z = f2b(f.z); o.w = f2b(f.w);
        *(ushort4*)(x_pack + off) = o;
    }
    __syncthreads();

    // ================= head-group loop (4 heads per group) =================
    for (int hg = 0; hg < 5; ++hg) {
        // ---- Phase A: qkv slice [64 x 240(pad 256)] via MFMA; wave w = n-tile ----
        if (w < 15) {
            f32x4 accA[4];
            #pragma unroll
            for (int mt = 0; mt < 4; ++mt) accA[mt] = (f32x4){0.f, 0.f, 0.f, 0.f};
            for (int kt = 0; kt < 10; ++kt) {
                short8 a[4];
                #pragma unroll
                for (int mt = 0; mt < 4; ++mt)
                    a[mt] = *(const short8*)(x_pack + ((mt * 10 + kt) * 64 + l) * 8);
                const short8 bf = *(const short8*)(wsp + ((long)(hg * 160 + kt * 16 + w) * 512) + l * 8);
                #pragma unroll
                for (int mt = 0; mt < 4; ++mt)
                    accA[mt] = __builtin_amdgcn_mfma_f32_16x16x32_bf16(a[mt], bf, accA[mt], 0, 0, 0);
            }
            // epilogue: +bias, cvt, scatter into qA/kB/vB layouts
            const int nl = w * 16 + (l & 15);          // < 240
            const int sel = nl / 80, within = nl % 80;
            const int h2 = within / 20, d = within % 20;
            const float bias = bqkv_s[sel * 400 + (hg * 4 + h2) * 20 + d];
            #pragma unroll
            for (int mt = 0; mt < 4; ++mt)
                #pragma unroll
                for (int ii = 0; ii < 4; ++ii) {
                    const int tok = mt * 16 + (l >> 4) * 4 + ii;
                    const unsigned short us = f2b(accA[mt][ii] + bias);
                    if (sel == 0) {
                        const int ld = (tok & 15) + (d >> 3) * 16;
                        trans[((h2 * 4 + mt) * 64 + ld) * 8 + (d & 7)] = us;
                    } else if (sel == 1) {
                        const int ld = (tok & 15) + (d >> 3) * 16;
                        trans[8192 + ((h2 * 4 + mt) * 64 + ld) * 8 + (d & 7)] = us;
                    } else {
                        const int ktv = tok >> 5;
                        const int ld  = (d & 15) + ((tok & 31) >> 3) * 16;
                        vB[(((h2 * 2 + ktv) * 2 + (d >> 4)) * 64 + ld) * 8 + (tok & 7)] = us;
                    }
                }
        }
        __syncthreads();

        // ---- Phase B: S = Q@K^T, exp -> pA; wave w = (h, jt) ----
        const int h  = w >> 2;
        {
            const int jt = w & 3;
            f32x4 accS[4];
            #pragma unroll
            for (int mt = 0; mt < 4; ++mt) accS[mt] = (f32x4){0.f, 0.f, 0.f, 0.f};
            short8 qa[4];
            #pragma unroll
            for (int mt = 0; mt < 4; ++mt)
                qa[mt] = *(const short8*)(trans + ((h * 4 + mt) * 64 + l) * 8);
            const short8 kb = *(const short8*)(trans + 8192 + ((h * 4 + jt) * 64 + l) * 8);
            #pragma unroll
            for (int mt = 0; mt < 4; ++mt)
                accS[mt] = __builtin_amdgcn_mfma_f32_16x16x32_bf16(qa[mt], kb, accS[mt], 0, 0, 0);
            __syncthreads();   // all qA/kB reads done before pA overlays
            const int jtok = jt * 16 + (l & 15);
            const int ktp = jtok >> 5;
            #pragma unroll
            for (int mt = 0; mt < 4; ++mt)
                #pragma unroll
                for (int ii = 0; ii < 4; ++ii) {
                    const int itok = mt * 16 + (l >> 4) * 4 + ii;
                    const float pv = __expf(accS[mt][ii] * 0.22360679774997896f);
                    const int ld = (itok & 15) + ((jtok & 31) >> 3) * 16;
                    trans[(((h * 4 + mt) * 2 + ktp) * 64 + ld) * 8 + (jtok & 7)] = f2b(pv);
                }
        }
        __syncthreads();

        // ---- Phase C: PV (+rowsum via ones col); wave w = (h, dnt, mh) ----
        {
            const int dnt = (w >> 1) & 1;
            const int mh  = w & 1;
            f32x4 accC[2];
            accC[0] = (f32x4){0.f, 0.f, 0.f, 0.f};
            accC[1] = (f32x4){0.f, 0.f, 0.f, 0.f};
            #pragma unroll
            for (int ktc = 0; ktc < 2; ++ktc) {
                const short8 vb = *(const short8*)(vB + (((h * 2 + ktc) * 2 + dnt) * 64 + l) * 8);
                #pragma unroll
                for (int mi = 0; mi < 2; ++mi) {
                    const int mt = mh * 2 + mi;
                    const short8 pa = *(const short8*)(trans + (((h * 4 + mt) * 2 + ktc) * 64 + l) * 8);
                    accC[mi] = __builtin_amdgcn_mfma_f32_16x16x32_bf16(pa, vb, accC[mi], 0, 0, 0);
                }
            }
            if (dnt == 1 && (l & 15) == 4) {
                #pragma unroll
                for (int mi = 0; mi < 2; ++mi)
                    #pragma unroll
                    for (int ii = 0; ii < 4; ++ii)
                        rsum_s[h * 64 + (mh * 2 + mi) * 16 + (l >> 4) * 4 + ii] = accC[mi][ii];
            }
            __syncthreads();   // rsum visible; all pA reads done
            // zero trans for next iteration (pads restored before next A-epilogue)
            if (hg < 4) {
                unsigned int* tz = (unsigned int*)trans;
                for (int i = t; i < 8192; i += 1024) tz[i] = 0u;
            }
            const int dloc = dnt * 16 + (l & 15);
            if (dloc < 20) {
                const int col = (hg * 4 + h) * 20 + dloc;
                const int ktx = col >> 5;
                const int ldx = ((col & 31) >> 3) * 16;
                #pragma unroll
                for (int mi = 0; mi < 2; ++mi) {
                    const int mt = mh * 2 + mi;
                    #pragma unroll
                    for (int ii = 0; ii < 4; ++ii) {
                        const int tok = mt * 16 + (l >> 4) * 4 + ii;
                        const float inv = 1.f / (rsum_s[h * 64 + tok] + 1e-8f);
                        ctxA[((mt * 13 + ktx) * 64 + (tok & 15) + ldx) * 8 + (col & 7)] =
                            f2b(accC[mi][ii] * inv);
                    }
                }
            }
        }
        __syncthreads();
    }

    // ---- Phase D: e = tanh(ctx@W1+b1); alpha_logit = e@W2; wave w = n-tile ----
    if (w < 13) {
        f32x4 accD[4];
        #pragma unroll
        for (int mt = 0; mt < 4; ++mt) accD[mt] = (f32x4){0.f, 0.f, 0.f, 0.f};
        for (int kt = 0; kt < 13; ++kt) {
            short8 ca[4];
            #pragma unroll
            for (int mt = 0; mt < 4; ++mt)
                ca[mt] = *(const short8*)(ctxA + ((mt * 13 + kt) * 64 + l) * 8);
            const short8 wb = *(const short8*)(wsp + W1_OFF_U16 + ((long)(kt * 13 + w) * 512) + l * 8);
            #pragma unroll
            for (int mt = 0; mt < 4; ++mt)
                accD[mt] = __builtin_amdgcn_mfma_f32_16x16x32_bf16(ca[mt], wb, accD[mt], 0, 0, 0);
        }
        const int colb = w * 16 + (l & 15);     // < 208; cols >=200 have b1=w2=0
        const float b1v = b1_s[colb], w2v = w2_s[colb];
        #pragma unroll
        for (int mt = 0; mt < 4; ++mt)
            #pragma unroll
            for (int ii = 0; ii < 4; ++ii) {
                const float x = accD[mt][ii] + b1v;
                const float ex = __expf(2.f * x);
                float v = ((ex - 1.f) / (ex + 1.f)) * w2v;
                v += __shfl_xor(v, 1, 64); v += __shfl_xor(v, 2, 64);
                v += __shfl_xor(v, 4, 64); v += __shfl_xor(v, 8, 64);
                if ((l & 15) == 0)
                    atomicAdd(&aacc_s[mt * 16 + (l >> 4) * 4 + ii], v);
            }
    }
    __syncthreads();

    // ---- alpha = exp(.) / (sum + 1e-8) ----
    if (t < 64) {
        const float a = __expf(aacc_s[t] + b2[0]);
        alpha_s[t] = a;
        float s = a;
        s += __shfl_xor(s, 32, 64); s += __shfl_xor(s, 16, 64);
        s += __shfl_xor(s, 8, 64);  s += __shfl_xor(s, 4, 64);
        s += __shfl_xor(s, 2, 64);  s += __shfl_xor(s, 1, 64);
        if (t == 0) inv_asum_s = 1.f / (s + 1e-8f);
    }
    __syncthreads();

    // ---- output: out[c] = sum_tok ctx[tok][c] * alpha[tok] * inv ----
    if (t < HD_) {
        const int c = t;
        const int ktx = c >> 5, ldo = ((c & 31) >> 3) * 16, el = c & 7;
        float a = 0.f;
        for (int tok = 0; tok < 64; ++tok) {
            const unsigned short us =
                ctxA[(((tok >> 4) * 13 + ktx) * 64 + (tok & 15) + ldo) * 8 + el];
            a = fmaf(b2f(us), alpha_s[tok], a);
        }
        out[(long)b * HD_ + c] = a * inv_asum_s;
    }
}

// ============================ fallback (R2, no ws) ============================
#define XS   324
#define CS   404
#define QS   21
#define SS   66

__global__ __launch_bounds__(512, 2)
void te_fused_fb(const int* __restrict__ text, const float* __restrict__ emb,
                 const float* __restrict__ WQ, const float* __restrict__ bQ,
                 const float* __restrict__ WK, const float* __restrict__ bK,
                 const float* __restrict__ WV, const float* __restrict__ bV,
                 const float* __restrict__ W1, const float* __restrict__ b1,
                 const float* __restrict__ W2, const float* __restrict__ b2,
                 float* __restrict__ out)
{
    __shared__ int            text_s[L_];
    __shared__ unsigned short x_s[L_ * XS];
    __shared__ unsigned short ctx_s[L_ * CS];
    __shared__ float          qkv_s[3 * 2 * L_ * QS];
    __shared__ unsigned short sc_s[2 * L_ * SS];
    __shared__ float          aacc_s[L_], alpha_s[L_];
    __shared__ float          inv_asum_s;

    const int b = blockIdx.x, t = threadIdx.x, lane = t & 63, wv = t >> 6;
    if (t < 64) text_s[t] = text[b * L_ + t];
    if (t >= 64 && t < 128) aacc_s[t - 64] = 0.f;
    __syncthreads();
    for (int u = t; u < L_ * 75; u += 512) {
        int l = u / 75, c4 = u - l * 75;
        const float4 f = *(const float4*)(emb + (long)text_s[l] * D_ + c4 * 4);
        ushort4 o; o.x = f2b(f.x); o.y = f2b(f.y); o.z = f2b(f.z); o.w = f2b(f.w);
        *(ushort4*)(x_s + l * XS + c4 * 4) = o;
    }
    __syncthreads();
    for (int hp = 0; hp < H_ / 2; ++hp) {
        const int h0 = hp * 2;
        if (t < 480) {
            const int rt = t & 15, ct = t >> 4, r0 = rt * 4, qc = ct * 4;
            const int sel = qc / 40, rem = qc - sel * 40, hh = rem / 20, cc = rem - hh * 20;
            const float* W = (sel == 0) ? WQ : (sel == 1) ? WK : WV;
            const float* bias = (sel == 0) ? bQ : (sel == 1) ? bK : bV;
            const int col0 = (h0 + hh) * 20 + cc;
            float acc[4][4];
            #pragma unroll
            for (int j = 0; j < 4; ++j) {
                const float bj = bias[col0 + j];
                acc[0][j] = bj; acc[1][j] = bj; acc[2][j] = bj; acc[3][j] = bj;
            }
            const float* Wp = W + col0;
            for (int c4 = 0; c4 < 75; ++c4) {
                const int d0 = c4 * 4;
                float xv[4][4]; float4 wvv[4];
                #pragma unroll
                for (int i = 0; i < 4; ++i) {
                    ushort4 xu = *(const ushort4*)(x_s + (r0 + i) * XS + d0);
                    xv[i][0] = b2f(xu.x); xv[i][1] = b2f(xu.y);
                    xv[i][2] = b2f(xu.z); xv[i][3] = b2f(xu.w);
                }
                #pragma unroll
                for (int dd = 0; dd < 4; ++dd)
                    wvv[dd] = *(const float4*)(Wp + (long)(d0 + dd) * HD_);
                #pragma unroll
                for (int dd = 0; dd < 4; ++dd)
                    #pragma unroll
                    for (int i = 0; i < 4; ++i) {
                        acc[i][0] = fmaf(xv[i][dd], wvv[dd].x, acc[i][0]);
                        acc[i][1] = fmaf(xv[i][dd], wvv[dd].y, acc[i][1]);
                        acc[i][2] = fmaf(xv[i][dd], wvv[dd].z, acc[i][2]);
                        acc[i][3] = fmaf(xv[i][dd], wvv[dd].w, acc[i][3]);
                    }
            }
            #pragma unroll
            for (int i = 0; i < 4; ++i)
                #pragma unroll
                for (int j = 0; j < 4; ++j)
                    qkv_s[((sel * 2 + hh) * L_ + r0 + i) * QS + cc + j] = acc[i][j];
        }
        __syncthreads();
        {
            const int j = lane, ig = wv & 3, hh = wv >> 2;
            float qreg[20], kreg[20];
            const float* qrow = &qkv_s[((0 * 2 + hh) * L_ + j) * QS];
            const float* krow = &qkv_s[((1 * 2 + hh) * L_ + j) * QS];
            #pragma unroll
            for (int d = 0; d < 20; ++d) { qreg[d] = qrow[d]; kreg[d] = krow[d]; }
            for (int ii = 0; ii < 16; ++ii) {
                const int i = ig * 16 + ii;
                float s = 0.f;
                #pragma unroll
                for (int d = 0; d < 20; ++d) s = fmaf(rlane(qreg[d], i), kreg[d], s);
                sc_s[(hh * L_ + i) * SS + j] = f2b(__expf(s * 0.22360679774997896f));
            }
        }
        __syncthreads();
        {
            const int i = lane, dg = wv, head = dg >> 2, dv0 = (dg & 3) * 5;
            float vreg[5];
            #pragma unroll
            for (int m = 0; m < 5; ++m)
                vreg[m] = qkv_s[((2 * 2 + head) * L_ + i) * QS + dv0 + m];
            float acc[5] = {0.f, 0.f, 0.f, 0.f, 0.f};
            float rsum = 0.f;
            const unsigned short* prow = &sc_s[(head * L_ + i) * SS];
            for (int jj = 0; jj < 64; ++jj) {
                const float p = b2f(prow[jj]);
                rsum += p;
                #pragma unroll
                for (int m = 0; m < 5; ++m) acc[m] = fmaf(p, rlane(vreg[m], jj), acc[m]);
            }
            const float inv = 1.f / (rsum + 1e-8f);
            const int col0 = (h0 + head) * 20 + dv0;
            #pragma unroll
            for (int m = 0; m < 5; ++m) ctx_s[i * CS + col0 + m] = f2b(acc[m] * inv);
        }
        __syncthreads();
    }
    for (int tau = t; tau < 800; tau += 512) {
        const int rt = tau & 15, cm = tau >> 4, r0 = rt * 4, m0 = cm * 4;
        float acc[4][4];
        #pragma unroll
        for (int j = 0; j < 4; ++j) {
            const float bj = b1[m0 + j];
            acc[0][j] = bj; acc[1][j] = bj; acc[2][j] = bj; acc[3][j] = bj;
        }
        for (int c4 = 0; c4 < 100; ++c4) {
            const int c0 = c4 * 4;
            float cv[4][4]; float4 wv1[4];
            #pragma unroll
            for (int i = 0; i < 4; ++i) {
                ushort4 cu = *(const ushort4*)(ctx_s + (r0 + i) * CS + c0);
                cv[i][0] = b2f(cu.x); cv[i][1] = b2f(cu.y);
                cv[i][2] = b2f(cu.z); cv[i][3] = b2f(cu.w);
            }
            #pragma unroll
            for (int dd = 0; dd < 4; ++dd)
                wv1[dd] = *(const float4*)(W1 + (long)(c0 + dd) * F1_ + m0);
            #pragma unroll
            for (int dd = 0; dd < 4; ++dd)
                #pragma unroll
                for (int i = 0; i < 4; ++i) {
                    acc[i][0] = fmaf(cv[i][dd], wv1[dd].x, acc[i][0]);
                    acc[i][1] = fmaf(cv[i][dd], wv1[dd].y, acc[i][1]);
                    acc[i][2] = fmaf(cv[i][dd], wv1[dd].z, acc[i][2]);
                    acc[i][3] = fmaf(cv[i][dd], wv1[dd].w, acc[i][3]);
                }
        }
        float w2l[4];
        #pragma unroll
        for (int j = 0; j < 4; ++j) w2l[j] = W2[m0 + j];
        #pragma unroll
        for (int i = 0; i < 4; ++i) {
            float ap = 0.f;
            #pragma unroll
            for (int j = 0; j < 4; ++j) ap += tanhf(acc[i][j]) * w2l[j];
            atomicAdd(&aacc_s[r0 + i], ap);
        }
    }
    __syncthreads();
    if (t < 64) {
        const float a = __expf(aacc_s[t] + b2[0]);
        alpha_s[t] = a;
        float s = a;
        s += __shfl_xor(s, 32, 64); s += __shfl_xor(s, 16, 64);
        s += __shfl_xor(s, 8, 64);  s += __shfl_xor(s, 4, 64);
        s += __shfl_xor(s, 2, 64);  s += __shfl_xor(s, 1, 64);
        if (t == 0) inv_asum_s = 1.f / (s + 1e-8f);
    }
    __syncthreads();
    if (t < HD_) {
        float a = 0.f;
        for (int l2 = 0; l2 < 64; ++l2)
            a = fmaf(b2f(ctx_s[l2 * CS + t]), alpha_s[l2], a);
        out[(long)b * HD_ + t] = a * inv_asum_s;
    }
}

extern "C" void kernel_launch(void* const* d_in, const int* in_sizes, int n_in,
                              void* d_out, int out_size, void* d_ws, size_t ws_size,
                              hipStream_t stream) {
    const int*   text = (const int*)d_in[0];
    const float* emb  = (const float*)d_in[1];
    const float* WQ   = (const float*)d_in[2];
    const float* bQ   = (const float*)d_in[3];
    const float* WK   = (const float*)d_in[4];
    const float* bK   = (const float*)d_in[5];
    const float* WV   = (const float*)d_in[6];
    const float* bV   = (const float*)d_in[7];
    const float* W1   = (const float*)d_in[8];
    const float* b1   = (const float*)d_in[9];
    const float* W2   = (const float*)d_in[10];
    const float* b2   = (const float*)d_in[11];
    float*       out  = (float*)d_out;

    if (ws_size >= (size_t)WS_NEEDED) {
        unsigned short* wsp = (unsigned short*)d_ws;
        const int total_frag_threads = (WQKV_TILES + W1_TILES) * 64;
        pack_weights<<<(total_frag_threads + 255) / 256, 256, 0, stream>>>(WQ, WK, WV, W1, wsp);
        te_mfma<<<B_, 1024, 0, stream>>>(text, emb, bQ, bK, bV, b1, W2, b2, wsp, out);
    } else {
        te_fused_fb<<<B_, 512, 0, stream>>>(text, emb, WQ, bQ, WK, bK, WV, bV,
                                            W1, b1, W2, b2, out);
    }
}

// Round 5
// 411.783 us; speedup vs baseline: 7.5073x; 1.0268x over previous
//
#include <hip/hip_runtime.h>
#include <hip/hip_bf16.h>

#define B_   2048
#define L_   64
#define H_   20
#define DK_  20
#define D_   300
#define HD_  400
#define F1_  200

typedef __attribute__((ext_vector_type(8))) short short8;
typedef __attribute__((ext_vector_type(4))) float f32x4;

// ---- workspace layout ----
// new path: [0, 992256) weight tiles (wqkv new layout + w1), ctx at CTX_OFF_B
// R4 path:  [0, 992256) weight tiles (wqkv old layout + w1)
#define WQKV_TILES   800
#define W1_TILES     169
#define W1_OFF_U16   409600          // 800 tiles * 512 us
#define WS_NEEDED    992256          // R4 path requirement
#define CTX_OFF_B    1048576         // 1 MB aligned
#define CTX_BYTES    (2048L * 64 * 400 * 2)
#define WS_FULL      (CTX_OFF_B + CTX_BYTES)

__device__ __forceinline__ float b2f(unsigned short u) {
    union { unsigned int i; float f; } v; v.i = ((unsigned int)u) << 16; return v.f;
}
__device__ __forceinline__ unsigned short f2b(float f) {
    union { float f; unsigned int i; } v; v.f = f;
    unsigned int x = v.i;
    return (unsigned short)((x + 0x7fffu + ((x >> 16) & 1u)) >> 16);  // RNE
}
__device__ __forceinline__ float rlane(float v, int l) {
    return __int_as_float(__builtin_amdgcn_readlane(__float_as_int(v), l));
}

// ==================== pack (NEW layout: hg=10 groups of 2 heads, nt=8) ====================
// wqkv frag = hg*80 + kt*8 + nt ; per hg columns [q(40) | k(40) | v(40) | pad(8)]
__global__ void pack_weights_new(const float* __restrict__ WQ, const float* __restrict__ WK,
                                 const float* __restrict__ WV, const float* __restrict__ W1,
                                 unsigned short* __restrict__ wsp)
{
    const int tid  = blockIdx.x * 256 + threadIdx.x;
    const int frag = tid >> 6, l = tid & 63;
    if (frag >= WQKV_TILES + W1_TILES) return;
    const int octet = l >> 4, lo = l & 15;
    unsigned short v[8];
    if (frag < WQKV_TILES) {
        const int hg = frag / 80, r = frag % 80, kt = r / 8, nt = r % 8;
        const int nl = nt * 16 + lo;                  // [0,128)
        const int sel = (nl < 120) ? nl / 40 : 0;
        const int within = nl % 40;
        const int h2 = within / 20, d = within % 20;
        const int col = (hg * 2 + h2) * 20 + d;
        const float* W = (sel == 0) ? WQ : (sel == 1) ? WK : WV;
        #pragma unroll
        for (int j = 0; j < 8; ++j) {
            const int k = kt * 32 + octet * 8 + j;
            const float f = (nl < 120 && k < 300) ? W[k * 400 + col] : 0.f;
            v[j] = f2b(f);
        }
    } else {
        const int f2 = frag - WQKV_TILES, kt = f2 / 13, nt = f2 % 13;
        const int n = nt * 16 + lo;
        #pragma unroll
        for (int j = 0; j < 8; ++j) {
            const int k = kt * 32 + octet * 8 + j;
            const float f = (n < 200 && k < 400) ? W1[k * 200 + n] : 0.f;
            v[j] = f2b(f);
        }
    }
    unsigned short* dst = wsp + (long)frag * 512 + l * 8;
    *(ushort4*)(dst)     = make_ushort4(v[0], v[1], v[2], v[3]);
    *(ushort4*)(dst + 4) = make_ushort4(v[4], v[5], v[6], v[7]);
}

// ==================== kernel 1: attention (512 thr, ~76 KB LDS, 2 blocks/CU) ====================
__global__ __launch_bounds__(512, 4)
void te_attn(const int* __restrict__ text,
             const float* __restrict__ emb,
             const float* __restrict__ bQ, const float* __restrict__ bK,
             const float* __restrict__ bV,
             const unsigned short* __restrict__ wsp,
             unsigned short* __restrict__ ctx_ws)
{
    __shared__ unsigned short x_pack[4 * 10 * 64 * 8];   // 40960 B  A-layout x
    // trans: qA tiles 0..7 (us 0..4095) + kB tiles 0..7 (us 4096..8191); overlaid by pA (16 tiles)
    __shared__ unsigned short trans[8192];               // 16384 B
    // vB: [h(2)][ktv(2)][dnt(2)] tiles; ones column at d==20 -> rowsum
    __shared__ unsigned short vB[4096];                  // 8192 B
    __shared__ unsigned short ctx_stage[64 * 40];        // 5120 B
    __shared__ float bqkv_s[1200];                       // 4800 B
    __shared__ float rsum_s[2 * 64];
    __shared__ int   text_s[64];

    const int b = blockIdx.x;
    const int t = threadIdx.x;
    const int l = t & 63;
    const int w = t >> 6;          // 0..7

    // ---- block init ----
    {
        unsigned int* xz = (unsigned int*)x_pack;
        for (int i = t; i < 10240; i += 512) xz[i] = 0u;
        unsigned int* tz = (unsigned int*)trans;
        for (int i = t; i < 4096; i += 512) tz[i] = 0u;
        unsigned int* vz = (unsigned int*)vB;
        for (int i = t; i < 2048; i += 512) {
            const int tile = i >> 8;            // 0..7
            const int lane = (i & 255) >> 2;
            vz[i] = ((tile & 1) == 1 && (lane & 15) == 4) ? 0x3F803F80u : 0u;
        }
        for (int i = t; i < 1200; i += 512)
            bqkv_s[i] = (i < 400) ? bQ[i] : (i < 800) ? bK[i - 400] : bV[i - 800];
        if (t < 64) text_s[t] = text[b * L_ + t];
    }
    __syncthreads();

    // ---- embedding gather -> x_pack (bf16 A-layout) ----
    for (int u = t; u < 64 * 75; u += 512) {
        const int r = u / 75, c4 = u - r * 75, k = c4 * 4;
        const float4 f = *(const float4*)(emb + (long)text_s[r] * D_ + k);
        const int mt = r >> 4, kt = k >> 5;
        const int ld = (r & 15) + ((k & 31) >> 3) * 16;
        const int off = ((mt * 10 + kt) * 64 + ld) * 8 + (k & 7);
        ushort4 o; o.x = f2b(f.x); o.y = f2b(f.y); o.z = f2b(f.z); o.w = f2b(f.w);
        *(ushort4*)(x_pack + off) = o;
    }
    __syncthreads();

    // ================= head-pair loop (2 heads per group, 10 groups) =================
    for (int hg = 0; hg < 10; ++hg) {
        // ---- A region: copy out previous hg's ctx_stage; Phase A MFMA ----
        if (hg > 0) {
            for (int u = t; u < 640; u += 512) {
                const int row = u / 10, c4 = u - row * 10;
                const ushort4 v = *(const ushort4*)(ctx_stage + row * 40 + c4 * 4);
                *(ushort4*)(ctx_ws + ((long)(b * 64 + row)) * 400 + (hg - 1) * 40 + c4 * 4) = v;
            }
        }
        {
            f32x4 accA[4];
            #pragma unroll
            for (int mt = 0; mt < 4; ++mt) accA[mt] = (f32x4){0.f, 0.f, 0.f, 0.f};
            for (int kt = 0; kt < 10; ++kt) {
                short8 a[4];
                #pragma unroll
                for (int mt = 0; mt < 4; ++mt)
                    a[mt] = *(const short8*)(x_pack + ((mt * 10 + kt) * 64 + l) * 8);
                const short8 bf = *(const short8*)(wsp + ((long)(hg * 80 + kt * 8 + w) * 512) + l * 8);
                #pragma unroll
                for (int mt = 0; mt < 4; ++mt)
                    accA[mt] = __builtin_amdgcn_mfma_f32_16x16x32_bf16(a[mt], bf, accA[mt], 0, 0, 0);
            }
            // epilogue: +bias, cvt, scatter into qA/kB/vB
            const int nl = w * 16 + (l & 15);      // [0,128)
            if (nl < 120) {
                const int sel = nl / 40, within = nl % 40;
                const int h2 = within / 20, d = within % 20;
                const float bias = bqkv_s[sel * 400 + (hg * 2 + h2) * 20 + d];
                #pragma unroll
                for (int mt = 0; mt < 4; ++mt)
                    #pragma unroll
                    for (int ii = 0; ii < 4; ++ii) {
                        const int tok = mt * 16 + (l >> 4) * 4 + ii;
                        const unsigned short us = f2b(accA[mt][ii] + bias);
                        if (sel == 0) {
                            const int ld = (tok & 15) + (d >> 3) * 16;
                            trans[((h2 * 4 + mt) * 64 + ld) * 8 + (d & 7)] = us;
                        } else if (sel == 1) {
                            const int ld = (tok & 15) + (d >> 3) * 16;
                            trans[4096 + ((h2 * 4 + (tok >> 4)) * 64 + ld) * 8 + (d & 7)] = us;
                        } else {
                            const int ktv = tok >> 5;
                            const int ld  = (d & 15) + ((tok & 31) >> 3) * 16;
                            vB[(((h2 * 2 + ktv) * 2 + (d >> 4)) * 64 + ld) * 8 + (tok & 7)] = us;
                        }
                    }
            }
        }
        __syncthreads();                                   // B1: qA/kB/vB visible

        // ---- Phase B: S = Q@K^T, exp -> pA; wave = (h, jt) ----
        const int h  = w >> 2;                             // 0..1
        {
            const int jt = w & 3;
            f32x4 accS[4];
            #pragma unroll
            for (int mt = 0; mt < 4; ++mt) accS[mt] = (f32x4){0.f, 0.f, 0.f, 0.f};
            short8 qa[4];
            #pragma unroll
            for (int mt = 0; mt < 4; ++mt)
                qa[mt] = *(const short8*)(trans + ((h * 4 + mt) * 64 + l) * 8);
            const short8 kb = *(const short8*)(trans + 4096 + ((h * 4 + jt) * 64 + l) * 8);
            #pragma unroll
            for (int mt = 0; mt < 4; ++mt)
                accS[mt] = __builtin_amdgcn_mfma_f32_16x16x32_bf16(qa[mt], kb, accS[mt], 0, 0, 0);
            __syncthreads();                               // B2: all qA/kB reads done
            const int jtok = jt * 16 + (l & 15);
            const int ktp = jtok >> 5;
            #pragma unroll
            for (int mt = 0; mt < 4; ++mt)
                #pragma unroll
                for (int ii = 0; ii < 4; ++ii) {
                    const int itok = mt * 16 + (l >> 4) * 4 + ii;
                    const float pv = __expf(accS[mt][ii] * 0.22360679774997896f);
                    const int ld = (itok & 15) + ((jtok & 31) >> 3) * 16;
                    trans[(((h * 4 + mt) * 2 + ktp) * 64 + ld) * 8 + (jtok & 7)] = f2b(pv);
                }
        }
        __syncthreads();                                   // B3: pA visible

        // ---- Phase C: PV (+rowsum via ones col); wave = (h, dnt, mh) ----
        {
            const int dnt = (w >> 1) & 1;
            const int mh  = w & 1;
            f32x4 accC[2];
            accC[0] = (f32x4){0.f, 0.f, 0.f, 0.f};
            accC[1] = (f32x4){0.f, 0.f, 0.f, 0.f};
            #pragma unroll
            for (int ktc = 0; ktc < 2; ++ktc) {
                const short8 vb = *(const short8*)(vB + (((h * 2 + ktc) * 2 + dnt) * 64 + l) * 8);
                #pragma unroll
                for (int mi = 0; mi < 2; ++mi) {
                    const int mt = mh * 2 + mi;
                    const short8 pa = *(const short8*)(trans + (((h * 4 + mt) * 2 + ktc) * 64 + l) * 8);
                    accC[mi] = __builtin_amdgcn_mfma_f32_16x16x32_bf16(pa, vb, accC[mi], 0, 0, 0);
                }
            }
            if (dnt == 1 && (l & 15) == 4) {
                #pragma unroll
                for (int mi = 0; mi < 2; ++mi)
                    #pragma unroll
                    for (int ii = 0; ii < 4; ++ii)
                        rsum_s[h * 64 + (mh * 2 + mi) * 16 + (l >> 4) * 4 + ii] = accC[mi][ii];
            }
            __syncthreads();                               // B4: rsum visible; pA reads done
            // re-zero trans so next A-epilogue's k-pads are clean
            if (hg < 9) {
                unsigned int* tz = (unsigned int*)trans;
                for (int i = t; i < 4096; i += 512) tz[i] = 0u;
            }
            const int dloc = dnt * 16 + (l & 15);
            if (dloc < 20) {
                const int cl = h * 20 + dloc;              // col within hg's 40
                #pragma unroll
                for (int mi = 0; mi < 2; ++mi) {
                    const int mt = mh * 2 + mi;
                    #pragma unroll
                    for (int ii = 0; ii < 4; ++ii) {
                        const int tok = mt * 16 + (l >> 4) * 4 + ii;
                        const float inv = 1.f / (rsum_s[h * 64 + tok] + 1e-8f);
                        ctx_stage[tok * 40 + cl] = f2b(accC[mi][ii] * inv);
                    }
                }
            }
        }
        __syncthreads();                                   // B5: ctx_stage + trans-zero visible
    }

    // tail: copy last hg's ctx_stage
    for (int u = t; u < 640; u += 512) {
        const int row = u / 10, c4 = u - row * 10;
        const ushort4 v = *(const ushort4*)(ctx_stage + row * 40 + c4 * 4);
        *(ushort4*)(ctx_ws + ((long)(b * 64 + row)) * 400 + 9 * 40 + c4 * 4) = v;
    }
}

// ==================== kernel 2: pooling (512 thr, ~55 KB LDS, 2 blocks/CU) ====================
__global__ __launch_bounds__(512, 4)
void te_pool(const unsigned short* __restrict__ ctx_ws,
             const float* __restrict__ b1, const float* __restrict__ W2,
             const float* __restrict__ b2,
             const unsigned short* __restrict__ wsp,
             float* __restrict__ out)
{
    __shared__ unsigned short ctxA[4 * 13 * 64 * 8];     // 53248 B
    __shared__ float b1_s[208], w2_s[208];
    __shared__ float aacc_s[64], alpha_s[64];
    __shared__ float inv_asum_s;

    const int b = blockIdx.x;
    const int t = threadIdx.x;
    const int l = t & 63;
    const int w = t >> 6;          // 0..7

    // zero kt=12 pad tiles (cols 384..415 region; real cols overwritten by gather)
    {
        unsigned int* cz = (unsigned int*)ctxA;
        for (int i = t; i < 1024; i += 512) {
            const int mt = i >> 8;
            cz[(mt * 13 + 12) * 256 + (i & 255)] = 0u;
        }
        if (t < 208) { b1_s[t] = (t < 200) ? b1[t] : 0.f; w2_s[t] = (t < 200) ? W2[t] : 0.f; }
        if (t >= 208 && t < 272) aacc_s[t - 208] = 0.f;
    }
    __syncthreads();

    // gather ctx rows -> A-layout
    for (int u = t; u < 6400; u += 512) {
        const int row = u / 100, c4 = u - row * 100;
        const int col = c4 * 4;
        const ushort4 v = *(const ushort4*)(ctx_ws + ((long)(b * 64 + row)) * 400 + col);
        const int mt = row >> 4, ktx = col >> 5;
        const int ld = (row & 15) + ((col & 31) >> 3) * 16;
        *(ushort4*)(ctxA + ((mt * 13 + ktx) * 64 + ld) * 8 + (col & 7)) = v;
    }
    __syncthreads();

    // Phase D: e = tanh(ctx@W1+b1); alpha_logit = e@W2
    {
        f32x4 accD[2][4];
        #pragma unroll
        for (int g = 0; g < 2; ++g)
            #pragma unroll
            for (int mt = 0; mt < 4; ++mt) accD[g][mt] = (f32x4){0.f, 0.f, 0.f, 0.f};
        const int nta = w, ntb = w + 8;                    // ntb valid if < 13
        for (int kt = 0; kt < 13; ++kt) {
            short8 ca[4];
            #pragma unroll
            for (int mt = 0; mt < 4; ++mt)
                ca[mt] = *(const short8*)(ctxA + ((mt * 13 + kt) * 64 + l) * 8);
            const short8 wb0 = *(const short8*)(wsp + W1_OFF_U16 + ((long)(kt * 13 + nta) * 512) + l * 8);
            #pragma unroll
            for (int mt = 0; mt < 4; ++mt)
                accD[0][mt] = __builtin_amdgcn_mfma_f32_16x16x32_bf16(ca[mt], wb0, accD[0][mt], 0, 0, 0);
            if (ntb < 13) {
                const short8 wb1 = *(const short8*)(wsp + W1_OFF_U16 + ((long)(kt * 13 + ntb) * 512) + l * 8);
                #pragma unroll
                for (int mt = 0; mt < 4; ++mt)
                    accD[1][mt] = __builtin_amdgcn_mfma_f32_16x16x32_bf16(ca[mt], wb1, accD[1][mt], 0, 0, 0);
            }
        }
        float part[4][4];
        #pragma unroll
        for (int mt = 0; mt < 4; ++mt)
            #pragma unroll
            for (int ii = 0; ii < 4; ++ii) part[mt][ii] = 0.f;
        #pragma unroll
        for (int g = 0; g < 2; ++g) {
            const int ntv = (g == 0) ? nta : ntb;
            if (ntv < 13) {
                const int colb = ntv * 16 + (l & 15);
                const float b1v = b1_s[colb], w2v = w2_s[colb];
                #pragma unroll
                for (int mt = 0; mt < 4; ++mt)
                    #pragma unroll
                    for (int ii = 0; ii < 4; ++ii) {
                        const float x = accD[g][mt][ii] + b1v;
                        const float ex = __expf(2.f * x);
                        part[mt][ii] += ((ex - 1.f) / (ex + 1.f)) * w2v;
                    }
            }
        }
        #pragma unroll
        for (int mt = 0; mt < 4; ++mt)
            #pragma unroll
            for (int ii = 0; ii < 4; ++ii) {
                float v = part[mt][ii];
                v += __shfl_xor(v, 1, 64); v += __shfl_xor(v, 2, 64);
                v += __shfl_xor(v, 4, 64); v += __shfl_xor(v, 8, 64);
                if ((l & 15) == 0)
                    atomicAdd(&aacc_s[mt * 16 + (l >> 4) * 4 + ii], v);
            }
    }
    __syncthreads();

    if (t < 64) {
        const float a = __expf(aacc_s[t] + b2[0]);
        alpha_s[t] = a;
        float s = a;
        s += __shfl_xor(s, 32, 64); s += __shfl_xor(s, 16, 64);
        s += __shfl_xor(s, 8, 64);  s += __shfl_xor(s, 4, 64);
        s += __shfl_xor(s, 2, 64);  s += __shfl_xor(s, 1, 64);
        if (t == 0) inv_asum_s = 1.f / (s + 1e-8f);
    }
    __syncthreads();

    if (t < HD_) {
        const int c = t;
        const int ktx = c >> 5, ldo = ((c & 31) >> 3) * 16, el = c & 7;
        float a = 0.f;
        for (int tok = 0; tok < 64; ++tok) {
            const unsigned short us =
                ctxA[(((tok >> 4) * 13 + ktx) * 64 + (tok & 15) + ldo) * 8 + el];
            a = fmaf(b2f(us), alpha_s[tok], a);
        }
        out[(long)b * HD_ + c] = a * inv_asum_s;
    }
}

// ==================== pack (OLD layout, for R4 fallback path) ====================
__global__ void pack_weights_old(const float* __restrict__ WQ, const float* __restrict__ WK,
                                 const float* __restrict__ WV, const float* __restrict__ W1,
                                 unsigned short* __restrict__ wsp)
{
    const int tid  = blockIdx.x * 256 + threadIdx.x;
    const int frag = tid >> 6, l = tid & 63;
    if (frag >= WQKV_TILES + W1_TILES) return;
    const int octet = l >> 4, lo = l & 15;
    unsigned short v[8];
    if (frag < WQKV_TILES) {
        const int hg = frag / 160, r = frag % 160, kt = r / 16, nt = r % 16;
        const int nl = nt * 16 + lo;
        const int sel = (nl < 240) ? nl / 80 : 0;
        const int within = nl % 80;
        const int h2 = within / 20, d = within % 20;
        const int col = (hg * 4 + h2) * 20 + d;
        const float* W = (sel == 0) ? WQ : (sel == 1) ? WK : WV;
        #pragma unroll
        for (int j = 0; j < 8; ++j) {
            const int k = kt * 32 + octet * 8 + j;
            const float f = (nl < 240 && k < 300) ? W[k * 400 + col] : 0.f;
            v[j] = f2b(f);
        }
    } else {
        const int f2 = frag - WQKV_TILES, kt = f2 / 13, nt = f2 % 13;
        const int n = nt * 16 + lo;
        #pragma unroll
        for (int j = 0; j < 8; ++j) {
            const int k = kt * 32 + octet * 8 + j;
            const float f = (n < 200 && k < 400) ? W1[k * 200 + n] : 0.f;
            v[j] = f2b(f);
        }
    }
    unsigned short* dst = wsp + (long)frag * 512 + l * 8;
    *(ushort4*)(dst)     = make_ushort4(v[0], v[1], v[2], v[3]);
    *(ushort4*)(dst + 4) = make_ushort4(v[4], v[5], v[6], v[7]);
}

// ==================== R4 fused kernel (fallback when ws < WS_FULL) ====================
__global__ __launch_bounds__(1024, 4)
void te_mfma(const int* __restrict__ text,
             const float* __restrict__ emb,
             const float* __restrict__ bQ, const float* __restrict__ bK,
             const float* __restrict__ bV, const float* __restrict__ b1,
             const float* __restrict__ W2, const float* __restrict__ b2,
             const unsigned short* __restrict__ wsp,
             float* __restrict__ out)
{
    __shared__ unsigned short x_pack[4 * 10 * 64 * 8];
    __shared__ unsigned short ctxA[4 * 13 * 64 * 8];
    __shared__ unsigned short trans[16384];
    __shared__ unsigned short vB[8192];
    __shared__ float rsum_s[4 * 64];
    __shared__ float bqkv_s[3 * 400];
    __shared__ float b1_s[208];
    __shared__ float w2_s[208];
    __shared__ int   text_s[64];
    __shared__ float aacc_s[64], alpha_s[64];
    __shared__ float inv_asum_s;

    const int b = blockIdx.x;
    const int t = threadIdx.x;
    const int l = t & 63;
    const int w = t >> 6;

    {
        unsigned int* xz = (unsigned int*)x_pack;
        for (int i = t; i < 10240; i += 1024) xz[i] = 0u;
        unsigned int* cz = (unsigned int*)ctxA;
        for (int i = t; i < 13312; i += 1024) cz[i] = 0u;
        unsigned int* tz = (unsigned int*)trans;
        for (int i = t; i < 8192; i += 1024) tz[i] = 0u;
        unsigned int* vz = (unsigned int*)vB;
        for (int i = t; i < 4096; i += 1024) {
            const int lane_v = (i >> 2) & 63;
            const int dnt    = (i >> 8) & 1;
            vz[i] = (dnt == 1 && (lane_v & 15) == 4) ? 0x3F803F80u : 0u;
        }
        for (int i = t; i < 1200; i += 1024)
            bqkv_s[i] = (i < 400) ? bQ[i] : (i < 800) ? bK[i - 400] : bV[i - 800];
        if (t < 208) { b1_s[t] = (t < 200) ? b1[t] : 0.f; w2_s[t] = (t < 200) ? W2[t] : 0.f; }
        if (t >= 208 && t < 272) aacc_s[t - 208] = 0.f;
        if (t >= 272 && t < 336) text_s[t - 272] = text[b * L_ + (t - 272)];
    }
    __syncthreads();

    for (int u = t; u < 64 * 75; u += 1024) {
        const int r = u / 75, c4 = u - r * 75, k = c4 * 4;
        const float4 f = *(const float4*)(emb + (long)text_s[r] * D_ + k);
        const int mt = r >> 4, kt = k >> 5;
        const int ld = (r & 15) + ((k & 31) >> 3) * 16;
        const int off = ((mt * 10 + kt) * 64 + ld) * 8 + (k & 7);
        ushort4 o; o.x = f2b(f.x); o.y = f2b(f.y); o.z = f2b(f.z); o.w = f2b(f.w);
        *(ushort4*)(x_pack + off) = o;
    }
    __syncthreads();

    for (int hg = 0; hg < 5; ++hg) {
        if (w < 15) {
            f32x4 accA[4];
            #pragma unroll
            for (int mt = 0; mt < 4; ++mt) accA[mt] = (f32x4){0.f, 0.f, 0.f, 0.f};
            for (int kt = 0; kt < 10; ++kt) {
                short8 a[4];
                #pragma unroll
                for (int mt = 0; mt < 4; ++mt)
                    a[mt] = *(const short8*)(x_pack + ((mt * 10 + kt) * 64 + l) * 8);
                const short8 bf = *(const short8*)(wsp + ((long)(hg * 160 + kt * 16 + w) * 512) + l * 8);
                #pragma unroll
                for (int mt = 0; mt < 4; ++mt)
                    accA[mt] = __builtin_amdgcn_mfma_f32_16x16x32_bf16(a[mt], bf, accA[mt], 0, 0, 0);
            }
            const int nl = w * 16 + (l & 15);
            const int sel = nl / 80, within = nl % 80;
            const int h2 = within / 20, d = within % 20;
            const float bias = bqkv_s[sel * 400 + (hg * 4 + h2) * 20 + d];
            #pragma unroll
            for (int mt = 0; mt < 4; ++mt)
                #pragma unroll
                for (int ii = 0; ii < 4; ++ii) {
                    const int tok = mt * 16 + (l >> 4) * 4 + ii;
                    const unsigned short us = f2b(accA[mt][ii] + bias);
                    if (sel == 0) {
                        const int ld = (tok & 15) + (d >> 3) * 16;
                        trans[((h2 * 4 + mt) * 64 + ld) * 8 + (d & 7)] = us;
                    } else if (sel == 1) {
                        const int ld = (tok & 15) + (d >> 3) * 16;
                        trans[8192 + ((h2 * 4 + mt) * 64 + ld) * 8 + (d & 7)] = us;
                    } else {
                        const int ktv = tok >> 5;
                        const int ld  = (d & 15) + ((tok & 31) >> 3) * 16;
                        vB[(((h2 * 2 + ktv) * 2 + (d >> 4)) * 64 + ld) * 8 + (tok & 7)] = us;
                    }
                }
        }
        __syncthreads();

        const int h  = w >> 2;
        {
            const int jt = w & 3;
            f32x4 accS[4];
            #pragma unroll
            for (int mt = 0; mt < 4; ++mt) accS[mt] = (f32x4){0.f, 0.f, 0.f, 0.f};
            short8 qa[4];
            #pragma unroll
            for (int mt = 0; mt < 4; ++mt)
                qa[mt] = *(const short8*)(trans + ((h * 4 + mt) * 64 + l) * 8);
            const short8 kb = *(const short8*)(trans + 8192 + ((h * 4 + jt) * 64 + l) * 8);
            #pragma unroll
            for (int mt = 0; mt < 4; ++mt)
                accS[mt] = __builtin_amdgcn_mfma_f32_16x16x32_bf16(qa[mt], kb, accS[mt], 0, 0, 0);
            __syncthreads();
            const int jtok = jt * 16 + (l & 15);
            const int ktp = jtok >> 5;
            #pragma unroll
            for (int mt = 0; mt < 4; ++mt)
                #pragma unroll
                for (int ii = 0; ii < 4; ++ii) {
                    const int itok = mt * 16 + (l >> 4) * 4 + ii;
                    const float pv = __expf(accS[mt][ii] * 0.22360679774997896f);
                    const int ld = (itok & 15) + ((jtok & 31) >> 3) * 16;
                    trans[(((h * 4 + mt) * 2 + ktp) * 64 + ld) * 8 + (jtok & 7)] = f2b(pv);
                }
        }
        __syncthreads();

        {
            const int dnt = (w >> 1) & 1;
            const int mh  = w & 1;
            f32x4 accC[2];
            accC[0] = (f32x4){0.f, 0.f, 0.f, 0.f};
            accC[1] = (f32x4){0.f, 0.f, 0.f, 0.f};
            #pragma unroll
            for (int ktc = 0; ktc < 2; ++ktc) {
                const short8 vb = *(const short8*)(vB + (((h * 2 + ktc) * 2 + dnt) * 64 + l) * 8);
                #pragma unroll
                for (int mi = 0; mi < 2; ++mi) {
                    const int mt = mh * 2 + mi;
                    const short8 pa = *(const short8*)(trans + (((h * 4 + mt) * 2 + ktc) * 64 + l) * 8);
                    accC[mi] = __builtin_amdgcn_mfma_f32_16x16x32_bf16(pa, vb, accC[mi], 0, 0, 0);
                }
            }
            if (dnt == 1 && (l & 15) == 4) {
                #pragma unroll
                for (int mi = 0; mi < 2; ++mi)
                    #pragma unroll
                    for (int ii = 0; ii < 4; ++ii)
                        rsum_s[h * 64 + (mh * 2 + mi) * 16 + (l >> 4) * 4 + ii] = accC[mi][ii];
            }
            __syncthreads();
            if (hg < 4) {
                unsigned int* tz = (unsigned int*)trans;
                for (int i = t; i < 8192; i += 1024) tz[i] = 0u;
            }
            const int dloc = dnt * 16 + (l & 15);
            if (dloc < 20) {
                const int col = (hg * 4 + h) * 20 + dloc;
                const int ktx = col >> 5;
                const int ldx = ((col & 31) >> 3) * 16;
                #pragma unroll
                for (int mi = 0; mi < 2; ++mi) {
                    const int mt = mh * 2 + mi;
                    #pragma unroll
                    for (int ii = 0; ii < 4; ++ii) {
                        const int tok = mt * 16 + (l >> 4) * 4 + ii;
                        const float inv = 1.f / (rsum_s[h * 64 + tok] + 1e-8f);
                        ctxA[((mt * 13 + ktx) * 64 + (tok & 15) + ldx) * 8 + (col & 7)] =
                            f2b(accC[mi][ii] * inv);
                    }
                }
            }
        }
        __syncthreads();
    }

    if (w < 13) {
        f32x4 accD[4];
        #pragma unroll
        for (int mt = 0; mt < 4; ++mt) accD[mt] = (f32x4){0.f, 0.f, 0.f, 0.f};
        for (int kt = 0; kt < 13; ++kt) {
            short8 ca[4];
            #pragma unroll
            for (int mt = 0; mt < 4; ++mt)
                ca[mt] = *(const short8*)(ctxA + ((mt * 13 + kt) * 64 + l) * 8);
            const short8 wb = *(const short8*)(wsp + W1_OFF_U16 + ((long)(kt * 13 + w) * 512) + l * 8);
            #pragma unroll
            for (int mt = 0; mt < 4; ++mt)
                accD[mt] = __builtin_amdgcn_mfma_f32_16x16x32_bf16(ca[mt], wb, accD[mt], 0, 0, 0);
        }
        const int colb = w * 16 + (l & 15);
        const float b1v = b1_s[colb], w2v = w2_s[colb];
        #pragma unroll
        for (int mt = 0; mt < 4; ++mt)
            #pragma unroll
            for (int ii = 0; ii < 4; ++ii) {
                const float x = accD[mt][ii] + b1v;
                const float ex = __expf(2.f * x);
                float v = ((ex - 1.f) / (ex + 1.f)) * w2v;
                v += __shfl_xor(v, 1, 64); v += __shfl_xor(v, 2, 64);
                v += __shfl_xor(v, 4, 64); v += __shfl_xor(v, 8, 64);
                if ((l & 15) == 0)
                    atomicAdd(&aacc_s[mt * 16 + (l >> 4) * 4 + ii], v);
            }
    }
    __syncthreads();

    if (t < 64) {
        const float a = __expf(aacc_s[t] + b2[0]);
        alpha_s[t] = a;
        float s = a;
        s += __shfl_xor(s, 32, 64); s += __shfl_xor(s, 16, 64);
        s += __shfl_xor(s, 8, 64);  s += __shfl_xor(s, 4, 64);
        s += __shfl_xor(s, 2, 64);  s += __shfl_xor(s, 1, 64);
        if (t == 0) inv_asum_s = 1.f / (s + 1e-8f);
    }
    __syncthreads();

    if (t < HD_) {
        const int c = t;
        const int ktx = c >> 5, ldo = ((c & 31) >> 3) * 16, el = c & 7;
        float a = 0.f;
        for (int tok = 0; tok < 64; ++tok) {
            const unsigned short us =
                ctxA[(((tok >> 4) * 13 + ktx) * 64 + (tok & 15) + ldo) * 8 + el];
            a = fmaf(b2f(us), alpha_s[tok], a);
        }
        out[(long)b * HD_ + c] = a * inv_asum_s;
    }
}

// ==================== last-resort fallback (no workspace) ====================
#define XS   324
#define CS   404
#define QS   21
#define SS   66

__global__ __launch_bounds__(512, 2)
void te_fused_fb(const int* __restrict__ text, const float* __restrict__ emb,
                 const float* __restrict__ WQ, const float* __restrict__ bQ,
                 const float* __restrict__ WK, const float* __restrict__ bK,
                 const float* __restrict__ WV, const float* __restrict__ bV,
                 const float* __restrict__ W1, const float* __restrict__ b1,
                 const float* __restrict__ W2, const float* __restrict__ b2,
                 float* __restrict__ out)
{
    __shared__ int            text_s[L_];
    __shared__ unsigned short x_s[L_ * XS];
    __shared__ unsigned short ctx_s[L_ * CS];
    __shared__ float          qkv_s[3 * 2 * L_ * QS];
    __shared__ unsigned short sc_s[2 * L_ * SS];
    __shared__ float          aacc_s[L_], alpha_s[L_];
    __shared__ float          inv_asum_s;

    const int b = blockIdx.x, t = threadIdx.x, lane = t & 63, wv = t >> 6;
    if (t < 64) text_s[t] = text[b * L_ + t];
    if (t >= 64 && t < 128) aacc_s[t - 64] = 0.f;
    __syncthreads();
    for (int u = t; u < L_ * 75; u += 512) {
        int l = u / 75, c4 = u - l * 75;
        const float4 f = *(const float4*)(emb + (long)text_s[l] * D_ + c4 * 4);
        ushort4 o; o.x = f2b(f.x); o.y = f2b(f.y); o.z = f2b(f.z); o.w = f2b(f.w);
        *(ushort4*)(x_s + l * XS + c4 * 4) = o;
    }
    __syncthreads();
    for (int hp = 0; hp < H_ / 2; ++hp) {
        const int h0 = hp * 2;
        if (t < 480) {
            const int rt = t & 15, ct = t >> 4, r0 = rt * 4, qc = ct * 4;
            const int sel = qc / 40, rem = qc - sel * 40, hh = rem / 20, cc = rem - hh * 20;
            const float* W = (sel == 0) ? WQ : (sel == 1) ? WK : WV;
            const float* bias = (sel == 0) ? bQ : (sel == 1) ? bK : bV;
            const int col0 = (h0 + hh) * 20 + cc;
            float acc[4][4];
            #pragma unroll
            for (int j = 0; j < 4; ++j) {
                const float bj = bias[col0 + j];
                acc[0][j] = bj; acc[1][j] = bj; acc[2][j] = bj; acc[3][j] = bj;
            }
            const float* Wp = W + col0;
            for (int c4 = 0; c4 < 75; ++c4) {
                const int d0 = c4 * 4;
                float xv[4][4]; float4 wvv[4];
                #pragma unroll
                for (int i = 0; i < 4; ++i) {
                    ushort4 xu = *(const ushort4*)(x_s + (r0 + i) * XS + d0);
                    xv[i][0] = b2f(xu.x); xv[i][1] = b2f(xu.y);
                    xv[i][2] = b2f(xu.z); xv[i][3] = b2f(xu.w);
                }
                #pragma unroll
                for (int dd = 0; dd < 4; ++dd)
                    wvv[dd] = *(const float4*)(Wp + (long)(d0 + dd) * HD_);
                #pragma unroll
                for (int dd = 0; dd < 4; ++dd)
                    #pragma unroll
                    for (int i = 0; i < 4; ++i) {
                        acc[i][0] = fmaf(xv[i][dd], wvv[dd].x, acc[i][0]);
                        acc[i][1] = fmaf(xv[i][dd], wvv[dd].y, acc[i][1]);
                        acc[i][2] = fmaf(xv[i][dd], wvv[dd].z, acc[i][2]);
                        acc[i][3] = fmaf(xv[i][dd], wvv[dd].w, acc[i][3]);
                    }
            }
            #pragma unroll
            for (int i = 0; i < 4; ++i)
                #pragma unroll
                for (int j = 0; j < 4; ++j)
                    qkv_s[((sel * 2 + hh) * L_ + r0 + i) * QS + cc + j] = acc[i][j];
        }
        __syncthreads();
        {
            const int j = lane, ig = wv & 3, hh = wv >> 2;
            float qreg[20], kreg[20];
            const float* qrow = &qkv_s[((0 * 2 + hh) * L_ + j) * QS];
            const float* krow = &qkv_s[((1 * 2 + hh) * L_ + j) * QS];
            #pragma unroll
            for (int d = 0; d < 20; ++d) { qreg[d] = qrow[d]; kreg[d] = krow[d]; }
            for (int ii = 0; ii < 16; ++ii) {
                const int i = ig * 16 + ii;
                float s = 0.f;
                #pragma unroll
                for (int d = 0; d < 20; ++d) s = fmaf(rlane(qreg[d], i), kreg[d], s);
                sc_s[(hh * L_ + i) * SS + j] = f2b(__expf(s * 0.22360679774997896f));
            }
        }
        __syncthreads();
        {
            const int i = lane, dg = wv, head = dg >> 2, dv0 = (dg & 3) * 5;
            float vreg[5];
            #pragma unroll
            for (int m = 0; m < 5; ++m)
                vreg[m] = qkv_s[((2 * 2 + head) * L_ + i) * QS + dv0 + m];
            float acc[5] = {0.f, 0.f, 0.f, 0.f, 0.f};
            float rsum = 0.f;
            const unsigned short* prow = &sc_s[(head * L_ + i) * SS];
            for (int jj = 0; jj < 64; ++jj) {
                const float p = b2f(prow[jj]);
                rsum += p;
                #pragma unroll
                for (int m = 0; m < 5; ++m) acc[m] = fmaf(p, rlane(vreg[m], jj), acc[m]);
            }
            const float inv = 1.f / (rsum + 1e-8f);
            const int col0 = (h0 + head) * 20 + dv0;
            #pragma unroll
            for (int m = 0; m < 5; ++m) ctx_s[i * CS + col0 + m] = f2b(acc[m] * inv);
        }
        __syncthreads();
    }
    for (int tau = t; tau < 800; tau += 512) {
        const int rt = tau & 15, cm = tau >> 4, r0 = rt * 4, m0 = cm * 4;
        float acc[4][4];
        #pragma unroll
        for (int j = 0; j < 4; ++j) {
            const float bj = b1[m0 + j];
            acc[0][j] = bj; acc[1][j] = bj; acc[2][j] = bj; acc[3][j] = bj;
        }
        for (int c4 = 0; c4 < 100; ++c4) {
            const int c0 = c4 * 4;
            float cv[4][4]; float4 wv1[4];
            #pragma unroll
            for (int i = 0; i < 4; ++i) {
                ushort4 cu = *(const ushort4*)(ctx_s + (r0 + i) * CS + c0);
                cv[i][0] = b2f(cu.x); cv[i][1] = b2f(cu.y);
                cv[i][2] = b2f(cu.z); cv[i][3] = b2f(cu.w);
            }
            #pragma unroll
            for (int dd = 0; dd < 4; ++dd)
                wv1[dd] = *(const float4*)(W1 + (long)(c0 + dd) * F1_ + m0);
            #pragma unroll
            for (int dd = 0; dd < 4; ++dd)
                #pragma unroll
                for (int i = 0; i < 4; ++i) {
                    acc[i][0] = fmaf(cv[i][dd], wv1[dd].x, acc[i][0]);
                    acc[i][1] = fmaf(cv[i][dd], wv1[dd].y, acc[i][1]);
                    acc[i][2] = fmaf(cv[i][dd], wv1[dd].z, acc[i][2]);
                    acc[i][3] = fmaf(cv[i][dd], wv1[dd].w, acc[i][3]);
                }
        }
        float w2l[4];
        #pragma unroll
        for (int j = 0; j < 4; ++j) w2l[j] = W2[m0 + j];
        #pragma unroll
        for (int i = 0; i < 4; ++i) {
            float ap = 0.f;
            #pragma unroll
            for (int j = 0; j < 4; ++j) ap += tanhf(acc[i][j]) * w2l[j];
            atomicAdd(&aacc_s[r0 + i], ap);
        }
    }
    __syncthreads();
    if (t < 64) {
        const float a = __expf(aacc_s[t] + b2[0]);
        alpha_s[t] = a;
        float s = a;
        s += __shfl_xor(s, 32, 64); s += __shfl_xor(s, 16, 64);
        s += __shfl_xor(s, 8, 64);  s += __shfl_xor(s, 4, 64);
        s += __shfl_xor(s, 2, 64);  s += __shfl_xor(s, 1, 64);
        if (t == 0) inv_asum_s = 1.f / (s + 1e-8f);
    }
    __syncthreads();
    if (t < HD_) {
        float a = 0.f;
        for (int l2 = 0; l2 < 64; ++l2)
            a = fmaf(b2f(ctx_s[l2 * CS + t]), alpha_s[l2], a);
        out[(long)b * HD_ + t] = a * inv_asum_s;
    }
}

extern "C" void kernel_launch(void* const* d_in, const int* in_sizes, int n_in,
                              void* d_out, int out_size, void* d_ws, size_t ws_size,
                              hipStream_t stream) {
    const int*   text = (const int*)d_in[0];
    const float* emb  = (const float*)d_in[1];
    const float* WQ   = (const float*)d_in[2];
    const float* bQ   = (const float*)d_in[3];
    const float* WK   = (const float*)d_in[4];
    const float* bK   = (const float*)d_in[5];
    const float* WV   = (const float*)d_in[6];
    const float* bV   = (const float*)d_in[7];
    const float* W1   = (const float*)d_in[8];
    const float* b1   = (const float*)d_in[9];
    const float* W2   = (const float*)d_in[10];
    const float* b2   = (const float*)d_in[11];
    float*       out  = (float*)d_out;

    const int total_frag_threads = (WQKV_TILES + W1_TILES) * 64;
    if (ws_size >= (size_t)WS_FULL) {
        unsigned short* wsp    = (unsigned short*)d_ws;
        unsigned short* ctx_ws = (unsigned short*)((char*)d_ws + CTX_OFF_B);
        pack_weights_new<<<(total_frag_threads + 255) / 256, 256, 0, stream>>>(WQ, WK, WV, W1, wsp);
        te_attn<<<B_, 512, 0, stream>>>(text, emb, bQ, bK, bV, wsp, ctx_ws);
        te_pool<<<B_, 512, 0, stream>>>(ctx_ws, b1, W2, b2, wsp, out);
    } else if (ws_size >= (size_t)WS_NEEDED) {
        unsigned short* wsp = (unsigned short*)d_ws;
        pack_weights_old<<<(total_frag_threads + 255) / 256, 256, 0, stream>>>(WQ, WK, WV, W1, wsp);
        te_mfma<<<B_, 1024, 0, stream>>>(text, emb, bQ, bK, bV, b1, W2, b2, wsp, out);
    } else {
        te_fused_fb<<<B_, 512, 0, stream>>>(text, emb, WQ, bQ, WK, bK, WV, bV,
                                            W1, b1, W2, b2, out);
    }
}

// Round 6
// 347.560 us; speedup vs baseline: 8.8945x; 1.1848x over previous
//
#include <hip/hip_runtime.h>
#include <hip/hip_bf16.h>

#define B_   2048
#define L_   64
#define H_   20
#define DK_  20
#define D_   300
#define HD_  400
#define F1_  200

typedef __attribute__((ext_vector_type(8))) short short8;
typedef __attribute__((ext_vector_type(4))) float f32x4;

// ---- workspace layout ----
#define WQKV_TILES   800             // hg(10) * kt(10) * nt(8)
#define W1_TILES     169             // kt(13) * nt(13)
#define W1_OFF_U16   409600          // 800 tiles * 512 us
#define CTX_OFF_B    1048576         // 1 MB aligned
#define CTX_BYTES    (2048L * 64 * 400 * 2)
#define WS_FULL      (CTX_OFF_B + CTX_BYTES)

__device__ __forceinline__ float b2f(unsigned short u) {
    union { unsigned int i; float f; } v; v.i = ((unsigned int)u) << 16; return v.f;
}
// HW round-to-nearest-even conversions (v_cvt_pk_bf16_f32)
__device__ __forceinline__ unsigned int f2b2(float a, float b) {
    union { __hip_bfloat162 h; unsigned int u; } cv;
    cv.h = __float22bfloat162_rn(make_float2(a, b));
    return cv.u;
}
__device__ __forceinline__ unsigned short f2b(float a) {
    union { __hip_bfloat16 h; unsigned short u; } cv;
    cv.h = __float2bfloat16(a);
    return cv.u;
}
__device__ __forceinline__ float rcpf(float x) { return __builtin_amdgcn_rcpf(x); }
__device__ __forceinline__ float rlane(float v, int l) {
    return __int_as_float(__builtin_amdgcn_readlane(__float_as_int(v), l));
}

// ==================== weight pre-pack ====================
// wqkv frag = hg*80 + kt*8 + nt ; per hg columns [q(40) | k(40) | v(40) | pad(8)]
// B-frag (16x16x32): lane holds B[k = kt*32+(lane>>4)*8+j][n = nt*16+(lane&15)]
__global__ void pack_weights_new(const float* __restrict__ WQ, const float* __restrict__ WK,
                                 const float* __restrict__ WV, const float* __restrict__ W1,
                                 unsigned short* __restrict__ wsp)
{
    const int tid  = blockIdx.x * 256 + threadIdx.x;
    const int frag = tid >> 6, l = tid & 63;
    if (frag >= WQKV_TILES + W1_TILES) return;
    const int octet = l >> 4, lo = l & 15;
    unsigned short v[8];
    if (frag < WQKV_TILES) {
        const int hg = frag / 80, r = frag % 80, kt = r / 8, nt = r % 8;
        const int nl = nt * 16 + lo;                  // [0,128)
        const int sel = (nl < 120) ? nl / 40 : 0;
        const int within = nl % 40;
        const int h2 = within / 20, d = within % 20;
        const int col = (hg * 2 + h2) * 20 + d;
        const float* W = (sel == 0) ? WQ : (sel == 1) ? WK : WV;
        #pragma unroll
        for (int j = 0; j < 8; ++j) {
            const int k = kt * 32 + octet * 8 + j;
            const float f = (nl < 120 && k < 300) ? W[k * 400 + col] : 0.f;
            v[j] = f2b(f);
        }
    } else {
        const int f2 = frag - WQKV_TILES, kt = f2 / 13, nt = f2 % 13;
        const int n = nt * 16 + lo;
        #pragma unroll
        for (int j = 0; j < 8; ++j) {
            const int k = kt * 32 + octet * 8 + j;
            const float f = (n < 200 && k < 400) ? W1[k * 200 + n] : 0.f;
            v[j] = f2b(f);
        }
    }
    unsigned short* dst = wsp + (long)frag * 512 + l * 8;
    *(ushort4*)(dst)     = make_ushort4(v[0], v[1], v[2], v[3]);
    *(ushort4*)(dst + 4) = make_ushort4(v[4], v[5], v[6], v[7]);
}

// ==================== te_attn helpers ====================
// A-step: compute QKV C-slabs for S head-groups into registers (bias pre-folded)
template<int S>
__device__ __forceinline__ void a_step(int hg0, int w, int l, bool act, int selbase,
                                       const unsigned short* xp,
                                       const unsigned short* __restrict__ wsp,
                                       const float* bq, f32x4 slab[][4])
{
    #pragma unroll
    for (int s = 0; s < S; ++s) {
        const float bv = act ? bq[selbase + (hg0 + s) * 40] : 0.f;
        #pragma unroll
        for (int mt = 0; mt < 4; ++mt) slab[s][mt] = (f32x4){bv, bv, bv, bv};
    }
    for (int kt = 0; kt < 10; ++kt) {
        short8 a[4];
        #pragma unroll
        for (int mt = 0; mt < 4; ++mt)
            a[mt] = *(const short8*)(xp + ((mt * 10 + kt) * 64 + l) * 8);
        #pragma unroll
        for (int s = 0; s < S; ++s) {
            const short8 bf = *(const short8*)(wsp + ((long)((hg0 + s) * 80 + kt * 8 + w) * 512) + l * 8);
            #pragma unroll
            for (int mt = 0; mt < 4; ++mt)
                slab[s][mt] = __builtin_amdgcn_mfma_f32_16x16x32_bf16(a[mt], bf, slab[s][mt], 0, 0, 0);
        }
    }
}

// per-head-group attention body (5 barriers)
__device__ __forceinline__ void attn_hg_body(
    int hg, const f32x4* sl, int b, int t, int l, int w,
    bool act, int sel, int baseQK, int baseV, int quad,
    unsigned short* trans, unsigned short* vBs, unsigned short* stage,
    float* rsum_s, unsigned short* __restrict__ ctx_ws)
{
    // 1) copy out previous hg's ctx slice (stage stable until this hg's Phase C)
    if (hg > 0) {
        for (int u = t; u < 640; u += 512) {
            const int row = u / 10, c4 = u - row * 10;
            const ushort4 v = *(const ushort4*)(stage + row * 40 + c4 * 4);
            *(ushort4*)(ctx_ws + ((long)(b * 64 + row)) * 400 + (hg - 1) * 40 + c4 * 4) = v;
        }
    }
    // 2) scatter this hg's QKV slab into qA/kB/vB layouts
    if (act) {
        const unsigned int u01a = f2b2(sl[0][0], sl[0][1]), u23a = f2b2(sl[0][2], sl[0][3]);
        const unsigned int u01b = f2b2(sl[1][0], sl[1][1]), u23b = f2b2(sl[1][2], sl[1][3]);
        const unsigned int u01c = f2b2(sl[2][0], sl[2][1]), u23c = f2b2(sl[2][2], sl[2][3]);
        const unsigned int u01d = f2b2(sl[3][0], sl[3][1]), u23d = f2b2(sl[3][2], sl[3][3]);
        const unsigned int p01[4] = {u01a, u01b, u01c, u01d};
        const unsigned int p23[4] = {u23a, u23b, u23c, u23d};
        if (sel < 2) {
            #pragma unroll
            for (int mt = 0; mt < 4; ++mt) {
                const int a0 = baseQK + mt * 512;
                trans[a0]      = (unsigned short)p01[mt];
                trans[a0 + 8]  = (unsigned short)(p01[mt] >> 16);
                trans[a0 + 16] = (unsigned short)p23[mt];
                trans[a0 + 24] = (unsigned short)(p23[mt] >> 16);
            }
        } else {
            #pragma unroll
            for (int mt = 0; mt < 4; ++mt) {
                const int bm = baseV + (mt >> 1) * 1024 + (mt & 1) * 256;
                #pragma unroll
                for (int ii = 0; ii < 4; ++ii) {
                    const int tq = quad * 4 + ii;
                    const unsigned int uu = (ii < 2) ? p01[mt] : p23[mt];
                    vBs[bm + (tq >> 3) * 128 + (tq & 7)] =
                        (unsigned short)((ii & 1) ? (uu >> 16) : uu);
                }
            }
        }
    }
    __syncthreads();                                   // B1: qA/kB/vB visible

    // 3) Phase B: S = Q@K^T, exp -> pA (overlays qA/kB)
    const int h = w >> 2, jt = w & 3;
    f32x4 accS[4];
    #pragma unroll
    for (int mt = 0; mt < 4; ++mt) accS[mt] = (f32x4){0.f, 0.f, 0.f, 0.f};
    {
        short8 qa[4];
        #pragma unroll
        for (int mt = 0; mt < 4; ++mt)
            qa[mt] = *(const short8*)(trans + ((h * 4 + mt) * 64 + l) * 8);
        const short8 kb = *(const short8*)(trans + 4096 + ((h * 4 + jt) * 64 + l) * 8);
        #pragma unroll
        for (int mt = 0; mt < 4; ++mt)
            accS[mt] = __builtin_amdgcn_mfma_f32_16x16x32_bf16(qa[mt], kb, accS[mt], 0, 0, 0);
    }
    __syncthreads();                                   // B2: qA/kB reads done before overlay
    {
        const int jtok = jt * 16 + (l & 15);
        const int ktp = jtok >> 5;
        #pragma unroll
        for (int mt = 0; mt < 4; ++mt) {
            const float e0 = __expf(accS[mt][0] * 0.22360679774997896f);
            const float e1 = __expf(accS[mt][1] * 0.22360679774997896f);
            const float e2 = __expf(accS[mt][2] * 0.22360679774997896f);
            const float e3 = __expf(accS[mt][3] * 0.22360679774997896f);
            const unsigned int u01 = f2b2(e0, e1), u23 = f2b2(e2, e3);
            const int a0 = (((h * 4 + mt) * 2 + ktp) * 64 + quad * 4 + ((jtok & 31) >> 3) * 16) * 8 + (jtok & 7);
            trans[a0]      = (unsigned short)u01;
            trans[a0 + 8]  = (unsigned short)(u01 >> 16);
            trans[a0 + 16] = (unsigned short)u23;
            trans[a0 + 24] = (unsigned short)(u23 >> 16);
        }
    }
    __syncthreads();                                   // B3: pA visible

    // 4) Phase C: PV (+rowsum via ones col)
    const int dnt = (w >> 1) & 1, mh = w & 1;
    f32x4 accC[2];
    accC[0] = (f32x4){0.f, 0.f, 0.f, 0.f};
    accC[1] = (f32x4){0.f, 0.f, 0.f, 0.f};
    #pragma unroll
    for (int ktc = 0; ktc < 2; ++ktc) {
        const short8 vb = *(const short8*)(vBs + (((h * 2 + ktc) * 2 + dnt) * 64 + l) * 8);
        #pragma unroll
        for (int mi = 0; mi < 2; ++mi) {
            const int mt = mh * 2 + mi;
            const short8 pa = *(const short8*)(trans + (((h * 4 + mt) * 2 + ktc) * 64 + l) * 8);
            accC[mi] = __builtin_amdgcn_mfma_f32_16x16x32_bf16(pa, vb, accC[mi], 0, 0, 0);
        }
    }
    if (dnt == 1 && (l & 15) == 4) {
        #pragma unroll
        for (int mi = 0; mi < 2; ++mi)
            #pragma unroll
            for (int ii = 0; ii < 4; ++ii)
                rsum_s[h * 64 + (mh * 2 + mi) * 16 + quad * 4 + ii] = accC[mi][ii];
    }
    __syncthreads();                                   // B4: rsum visible; pA reads done
    if (hg < 9) {                                      // restore k-pad zeros for next scatter
        unsigned int* tz = (unsigned int*)trans;
        for (int i = t; i < 4096; i += 512) tz[i] = 0u;
    }
    {
        const int dloc = dnt * 16 + (l & 15);
        if (dloc < 20) {
            const int cl = h * 20 + dloc;
            #pragma unroll
            for (int mi = 0; mi < 2; ++mi) {
                const int mt = mh * 2 + mi;
                float vv[4];
                #pragma unroll
                for (int ii = 0; ii < 4; ++ii) {
                    const int tok = mt * 16 + quad * 4 + ii;
                    vv[ii] = accC[mi][ii] * rcpf(rsum_s[h * 64 + tok] + 1e-8f);
                }
                const unsigned int u01 = f2b2(vv[0], vv[1]), u23 = f2b2(vv[2], vv[3]);
                const int base = (mt * 16 + quad * 4) * 40 + cl;
                stage[base]       = (unsigned short)u01;
                stage[base + 40]  = (unsigned short)(u01 >> 16);
                stage[base + 80]  = (unsigned short)u23;
                stage[base + 120] = (unsigned short)(u23 >> 16);
            }
        }
    }
    __syncthreads();                                   // B5
}

// ==================== kernel 1: attention ====================
__global__ __launch_bounds__(512, 4)
void te_attn(const int* __restrict__ text,
             const float* __restrict__ emb,
             const float* __restrict__ bQ, const float* __restrict__ bK,
             const float* __restrict__ bV,
             const unsigned short* __restrict__ wsp,
             unsigned short* __restrict__ ctx_ws)
{
    __shared__ unsigned short x_pack[4 * 10 * 64 * 8];   // 40960 B  A-layout x
    __shared__ unsigned short trans[8192];               // qA(0..4095)+kB(4096..8191); pA overlay
    __shared__ unsigned short vB[4096];                  // ones col at d==20 -> rowsum
    __shared__ unsigned short ctx_stage[64 * 40];
    __shared__ float bqkv_s[1200];
    __shared__ float rsum_s[128];
    __shared__ int   text_s[64];

    const int b = blockIdx.x;
    const int t = threadIdx.x;
    const int l = t & 63;
    const int w = t >> 6;          // 0..7
    const int quad = l >> 4;

    // ---- block init ----
    {
        unsigned int* xz = (unsigned int*)x_pack;
        for (int i = t; i < 10240; i += 512) xz[i] = 0u;
        unsigned int* tz = (unsigned int*)trans;
        for (int i = t; i < 4096; i += 512) tz[i] = 0u;
        unsigned int* vz = (unsigned int*)vB;
        for (int i = t; i < 2048; i += 512) {
            const int tile = i >> 8;
            const int lane_v = (i & 255) >> 2;
            vz[i] = ((tile & 1) == 1 && (lane_v & 15) == 4) ? 0x3F803F80u : 0u;
        }
        for (int i = t; i < 1200; i += 512)
            bqkv_s[i] = (i < 400) ? bQ[i] : (i < 800) ? bK[i - 400] : bV[i - 800];
        if (t < 64) text_s[t] = text[b * L_ + t];
    }
    __syncthreads();

    // ---- embedding gather -> x_pack (bf16 A-layout) ----
    for (int u = t; u < 64 * 75; u += 512) {
        const int r = u / 75, c4 = u - r * 75, k = c4 * 4;
        const float4 f = *(const float4*)(emb + (long)text_s[r] * D_ + k);
        const int mt = r >> 4, kt = k >> 5;
        const int ld = (r & 15) + ((k & 31) >> 3) * 16;
        const unsigned int u01 = f2b2(f.x, f.y), u23 = f2b2(f.z, f.w);
        *(uint2*)(x_pack + ((mt * 10 + kt) * 64 + ld) * 8 + (k & 7)) = make_uint2(u01, u23);
    }
    __syncthreads();

    // ---- per-thread loop-invariant scatter constants ----
    const int nl = w * 16 + (l & 15);
    const bool act = nl < 120;
    int sel = 0, h2 = 0, d = 0;
    if (act) { sel = nl / 40; const int within = nl % 40; h2 = within / 20; d = within % 20; }
    const int baseQK = h2 * 2048 + (quad * 4 + (d >> 3) * 16) * 8 + (d & 7) + ((sel == 1) ? 4096 : 0);
    const int baseV  = h2 * 2048 + (d >> 4) * 512 + (d & 15) * 8;
    const int selbase = sel * 400 + h2 * 20 + d;

    f32x4 slab[4][4];
    // step 0: hg 0..3
    a_step<4>(0, w, l, act, selbase, x_pack, wsp, bqkv_s, slab);
    attn_hg_body(0, slab[0], b, t, l, w, act, sel, baseQK, baseV, quad, trans, vB, ctx_stage, rsum_s, ctx_ws);
    attn_hg_body(1, slab[1], b, t, l, w, act, sel, baseQK, baseV, quad, trans, vB, ctx_stage, rsum_s, ctx_ws);
    attn_hg_body(2, slab[2], b, t, l, w, act, sel, baseQK, baseV, quad, trans, vB, ctx_stage, rsum_s, ctx_ws);
    attn_hg_body(3, slab[3], b, t, l, w, act, sel, baseQK, baseV, quad, trans, vB, ctx_stage, rsum_s, ctx_ws);
    // step 1: hg 4..6
    a_step<3>(4, w, l, act, selbase, x_pack, wsp, bqkv_s, slab);
    attn_hg_body(4, slab[0], b, t, l, w, act, sel, baseQK, baseV, quad, trans, vB, ctx_stage, rsum_s, ctx_ws);
    attn_hg_body(5, slab[1], b, t, l, w, act, sel, baseQK, baseV, quad, trans, vB, ctx_stage, rsum_s, ctx_ws);
    attn_hg_body(6, slab[2], b, t, l, w, act, sel, baseQK, baseV, quad, trans, vB, ctx_stage, rsum_s, ctx_ws);
    // step 2: hg 7..9
    a_step<3>(7, w, l, act, selbase, x_pack, wsp, bqkv_s, slab);
    attn_hg_body(7, slab[0], b, t, l, w, act, sel, baseQK, baseV, quad, trans, vB, ctx_stage, rsum_s, ctx_ws);
    attn_hg_body(8, slab[1], b, t, l, w, act, sel, baseQK, baseV, quad, trans, vB, ctx_stage, rsum_s, ctx_ws);
    attn_hg_body(9, slab[2], b, t, l, w, act, sel, baseQK, baseV, quad, trans, vB, ctx_stage, rsum_s, ctx_ws);

    // tail: copy last hg's ctx slice
    for (int u = t; u < 640; u += 512) {
        const int row = u / 10, c4 = u - row * 10;
        const ushort4 v = *(const ushort4*)(ctx_stage + row * 40 + c4 * 4);
        *(ushort4*)(ctx_ws + ((long)(b * 64 + row)) * 400 + 9 * 40 + c4 * 4) = v;
    }
}

// ==================== kernel 2: pooling ====================
__global__ __launch_bounds__(512, 4)
void te_pool(const unsigned short* __restrict__ ctx_ws,
             const float* __restrict__ b1, const float* __restrict__ W2,
             const float* __restrict__ b2,
             const unsigned short* __restrict__ wsp,
             float* __restrict__ out)
{
    __shared__ unsigned short ctxA[4 * 13 * 64 * 8];     // 53248 B
    __shared__ float b1_s[208], w2_s[208];
    __shared__ float aacc_s[64], alpha_s[64];
    __shared__ float inv_asum_s;

    const int b = blockIdx.x;
    const int t = threadIdx.x;
    const int l = t & 63;
    const int w = t >> 6;

    {
        unsigned int* cz = (unsigned int*)ctxA;
        for (int i = t; i < 1024; i += 512) {
            const int mt = i >> 8;
            cz[(mt * 13 + 12) * 256 + (i & 255)] = 0u;   // kt=12 pad tiles
        }
        if (t < 208) { b1_s[t] = (t < 200) ? b1[t] : 0.f; w2_s[t] = (t < 200) ? W2[t] : 0.f; }
        if (t >= 208 && t < 272) aacc_s[t - 208] = 0.f;
    }
    __syncthreads();

    // gather ctx rows -> A-layout, 16B chunks
    for (int u = t; u < 3200; u += 512) {
        const int row = u / 50, c8 = u - row * 50;
        const int col = c8 * 8;
        const short8 v = *(const short8*)(ctx_ws + ((long)(b * 64 + row)) * 400 + col);
        const int mt = row >> 4, ktx = col >> 5;
        *(short8*)(ctxA + ((mt * 13 + ktx) * 64 + (row & 15) + ((col & 31) >> 3) * 16) * 8) = v;
    }
    __syncthreads();

    // Phase D: e = tanh(ctx@W1+b1); alpha_logit = e@W2
    {
        f32x4 accD[2][4];
        #pragma unroll
        for (int g = 0; g < 2; ++g)
            #pragma unroll
            for (int mt = 0; mt < 4; ++mt) accD[g][mt] = (f32x4){0.f, 0.f, 0.f, 0.f};
        const int nta = w, ntb = w + 8;
        for (int kt = 0; kt < 13; ++kt) {
            short8 ca[4];
            #pragma unroll
            for (int mt = 0; mt < 4; ++mt)
                ca[mt] = *(const short8*)(ctxA + ((mt * 13 + kt) * 64 + l) * 8);
            const short8 wb0 = *(const short8*)(wsp + W1_OFF_U16 + ((long)(kt * 13 + nta) * 512) + l * 8);
            #pragma unroll
            for (int mt = 0; mt < 4; ++mt)
                accD[0][mt] = __builtin_amdgcn_mfma_f32_16x16x32_bf16(ca[mt], wb0, accD[0][mt], 0, 0, 0);
            if (ntb < 13) {
                const short8 wb1 = *(const short8*)(wsp + W1_OFF_U16 + ((long)(kt * 13 + ntb) * 512) + l * 8);
                #pragma unroll
                for (int mt = 0; mt < 4; ++mt)
                    accD[1][mt] = __builtin_amdgcn_mfma_f32_16x16x32_bf16(ca[mt], wb1, accD[1][mt], 0, 0, 0);
            }
        }
        float part[4][4];
        #pragma unroll
        for (int mt = 0; mt < 4; ++mt)
            #pragma unroll
            for (int ii = 0; ii < 4; ++ii) part[mt][ii] = 0.f;
        #pragma unroll
        for (int g = 0; g < 2; ++g) {
            const int ntv = (g == 0) ? nta : ntb;
            if (ntv < 13) {
                const int colb = ntv * 16 + (l & 15);
                const float b1v = b1_s[colb], w2v = w2_s[colb];
                #pragma unroll
                for (int mt = 0; mt < 4; ++mt)
                    #pragma unroll
                    for (int ii = 0; ii < 4; ++ii) {
                        const float x = accD[g][mt][ii] + b1v;
                        const float ex = __expf(2.f * x);
                        const float th = 1.f - 2.f * rcpf(ex + 1.f);   // tanh via rcp
                        part[mt][ii] += th * w2v;
                    }
            }
        }
        #pragma unroll
        for (int mt = 0; mt < 4; ++mt)
            #pragma unroll
            for (int ii = 0; ii < 4; ++ii) {
                float v = part[mt][ii];
                v += __shfl_xor(v, 1, 64); v += __shfl_xor(v, 2, 64);
                v += __shfl_xor(v, 4, 64); v += __shfl_xor(v, 8, 64);
                if ((l & 15) == 0)
                    atomicAdd(&aacc_s[mt * 16 + (l >> 4) * 4 + ii], v);
            }
    }
    __syncthreads();

    if (t < 64) {
        const float a = __expf(aacc_s[t] + b2[0]);
        alpha_s[t] = a;
        float s = a;
        s += __shfl_xor(s, 32, 64); s += __shfl_xor(s, 16, 64);
        s += __shfl_xor(s, 8, 64);  s += __shfl_xor(s, 4, 64);
        s += __shfl_xor(s, 2, 64);  s += __shfl_xor(s, 1, 64);
        if (t == 0) inv_asum_s = 1.f / (s + 1e-8f);
    }
    __syncthreads();

    if (t < HD_) {
        const int c = t;
        const int ktx = c >> 5, ldo = ((c & 31) >> 3) * 16, el = c & 7;
        float a = 0.f;
        for (int tok = 0; tok < 64; ++tok) {
            const unsigned short us =
                ctxA[(((tok >> 4) * 13 + ktx) * 64 + (tok & 15) + ldo) * 8 + el];
            a = fmaf(b2f(us), alpha_s[tok], a);
        }
        out[(long)b * HD_ + c] = a * inv_asum_s;
    }
}

// ==================== last-resort fallback (no workspace) ====================
#define XS   324
#define CS   404
#define QS   21
#define SS   66

__global__ __launch_bounds__(512, 2)
void te_fused_fb(const int* __restrict__ text, const float* __restrict__ emb,
                 const float* __restrict__ WQ, const float* __restrict__ bQ,
                 const float* __restrict__ WK, const float* __restrict__ bK,
                 const float* __restrict__ WV, const float* __restrict__ bV,
                 const float* __restrict__ W1, const float* __restrict__ b1,
                 const float* __restrict__ W2, const float* __restrict__ b2,
                 float* __restrict__ out)
{
    __shared__ int            text_s[L_];
    __shared__ unsigned short x_s[L_ * XS];
    __shared__ unsigned short ctx_s[L_ * CS];
    __shared__ float          qkv_s[3 * 2 * L_ * QS];
    __shared__ unsigned short sc_s[2 * L_ * SS];
    __shared__ float          aacc_s[L_], alpha_s[L_];
    __shared__ float          inv_asum_s;

    const int b = blockIdx.x, t = threadIdx.x, lane = t & 63, wv = t >> 6;
    if (t < 64) text_s[t] = text[b * L_ + t];
    if (t >= 64 && t < 128) aacc_s[t - 64] = 0.f;
    __syncthreads();
    for (int u = t; u < L_ * 75; u += 512) {
        int l = u / 75, c4 = u - l * 75;
        const float4 f = *(const float4*)(emb + (long)text_s[l] * D_ + c4 * 4);
        ushort4 o; o.x = f2b(f.x); o.y = f2b(f.y); o.z = f2b(f.z); o.w = f2b(f.w);
        *(ushort4*)(x_s + l * XS + c4 * 4) = o;
    }
    __syncthreads();
    for (int hp = 0; hp < H_ / 2; ++hp) {
        const int h0 = hp * 2;
        if (t < 480) {
            const int rt = t & 15, ct = t >> 4, r0 = rt * 4, qc = ct * 4;
            const int sel = qc / 40, rem = qc - sel * 40, hh = rem / 20, cc = rem - hh * 20;
            const float* W = (sel == 0) ? WQ : (sel == 1) ? WK : WV;
            const float* bias = (sel == 0) ? bQ : (sel == 1) ? bK : bV;
            const int col0 = (h0 + hh) * 20 + cc;
            float acc[4][4];
            #pragma unroll
            for (int j = 0; j < 4; ++j) {
                const float bj = bias[col0 + j];
                acc[0][j] = bj; acc[1][j] = bj; acc[2][j] = bj; acc[3][j] = bj;
            }
            const float* Wp = W + col0;
            for (int c4 = 0; c4 < 75; ++c4) {
                const int d0 = c4 * 4;
                float xv[4][4]; float4 wvv[4];
                #pragma unroll
                for (int i = 0; i < 4; ++i) {
                    ushort4 xu = *(const ushort4*)(x_s + (r0 + i) * XS + d0);
                    xv[i][0] = b2f(xu.x); xv[i][1] = b2f(xu.y);
                    xv[i][2] = b2f(xu.z); xv[i][3] = b2f(xu.w);
                }
                #pragma unroll
                for (int dd = 0; dd < 4; ++dd)
                    wvv[dd] = *(const float4*)(Wp + (long)(d0 + dd) * HD_);
                #pragma unroll
                for (int dd = 0; dd < 4; ++dd)
                    #pragma unroll
                    for (int i = 0; i < 4; ++i) {
                        acc[i][0] = fmaf(xv[i][dd], wvv[dd].x, acc[i][0]);
                        acc[i][1] = fmaf(xv[i][dd], wvv[dd].y, acc[i][1]);
                        acc[i][2] = fmaf(xv[i][dd], wvv[dd].z, acc[i][2]);
                        acc[i][3] = fmaf(xv[i][dd], wvv[dd].w, acc[i][3]);
                    }
            }
            #pragma unroll
            for (int i = 0; i < 4; ++i)
                #pragma unroll
                for (int j = 0; j < 4; ++j)
                    qkv_s[((sel * 2 + hh) * L_ + r0 + i) * QS + cc + j] = acc[i][j];
        }
        __syncthreads();
        {
            const int j = lane, ig = wv & 3, hh = wv >> 2;
            float qreg[20], kreg[20];
            const float* qrow = &qkv_s[((0 * 2 + hh) * L_ + j) * QS];
            const float* krow = &qkv_s[((1 * 2 + hh) * L_ + j) * QS];
            #pragma unroll
            for (int dd = 0; dd < 20; ++dd) { qreg[dd] = qrow[dd]; kreg[dd] = krow[dd]; }
            for (int ii = 0; ii < 16; ++ii) {
                const int i = ig * 16 + ii;
                float s = 0.f;
                #pragma unroll
                for (int dd = 0; dd < 20; ++dd) s = fmaf(rlane(qreg[dd], i), kreg[dd], s);
                sc_s[(hh * L_ + i) * SS + j] = f2b(__expf(s * 0.22360679774997896f));
            }
        }
        __syncthreads();
        {
            const int i = lane, dg = wv, head = dg >> 2, dv0 = (dg & 3) * 5;
            float vreg[5];
            #pragma unroll
            for (int m = 0; m < 5; ++m)
                vreg[m] = qkv_s[((2 * 2 + head) * L_ + i) * QS + dv0 + m];
            float acc[5] = {0.f, 0.f, 0.f, 0.f, 0.f};
            float rsum = 0.f;
            const unsigned short* prow = &sc_s[(head * L_ + i) * SS];
            for (int jj = 0; jj < 64; ++jj) {
                const float p = b2f(prow[jj]);
                rsum += p;
                #pragma unroll
                for (int m = 0; m < 5; ++m) acc[m] = fmaf(p, rlane(vreg[m], jj), acc[m]);
            }
            const float inv = 1.f / (rsum + 1e-8f);
            const int col0 = (h0 + head) * 20 + dv0;
            #pragma unroll
            for (int m = 0; m < 5; ++m) ctx_s[i * CS + col0 + m] = f2b(acc[m] * inv);
        }
        __syncthreads();
    }
    for (int tau = t; tau < 800; tau += 512) {
        const int rt = tau & 15, cm = tau >> 4, r0 = rt * 4, m0 = cm * 4;
        float acc[4][4];
        #pragma unroll
        for (int j = 0; j < 4; ++j) {
            const float bj = b1[m0 + j];
            acc[0][j] = bj; acc[1][j] = bj; acc[2][j] = bj; acc[3][j] = bj;
        }
        for (int c4 = 0; c4 < 100; ++c4) {
            const int c0 = c4 * 4;
            float cv[4][4]; float4 wv1[4];
            #pragma unroll
            for (int i = 0; i < 4; ++i) {
                ushort4 cu = *(const ushort4*)(ctx_s + (r0 + i) * CS + c0);
                cv[i][0] = b2f(cu.x); cv[i][1] = b2f(cu.y);
                cv[i][2] = b2f(cu.z); cv[i][3] = b2f(cu.w);
            }
            #pragma unroll
            for (int dd = 0; dd < 4; ++dd)
                wv1[dd] = *(const float4*)(W1 + (long)(c0 + dd) * F1_ + m0);
            #pragma unroll
            for (int dd = 0; dd < 4; ++dd)
                #pragma unroll
                for (int i = 0; i < 4; ++i) {
                    acc[i][0] = fmaf(cv[i][dd], wv1[dd].x, acc[i][0]);
                    acc[i][1] = fmaf(cv[i][dd], wv1[dd].y, acc[i][1]);
                    acc[i][2] = fmaf(cv[i][dd], wv1[dd].z, acc[i][2]);
                    acc[i][3] = fmaf(cv[i][dd], wv1[dd].w, acc[i][3]);
                }
        }
        float w2l[4];
        #pragma unroll
        for (int j = 0; j < 4; ++j) w2l[j] = W2[m0 + j];
        #pragma unroll
        for (int i = 0; i < 4; ++i) {
            float ap = 0.f;
            #pragma unroll
            for (int j = 0; j < 4; ++j) ap += tanhf(acc[i][j]) * w2l[j];
            atomicAdd(&aacc_s[r0 + i], ap);
        }
    }
    __syncthreads();
    if (t < 64) {
        const float a = __expf(aacc_s[t] + b2[0]);
        alpha_s[t] = a;
        float s = a;
        s += __shfl_xor(s, 32, 64); s += __shfl_xor(s, 16, 64);
        s += __shfl_xor(s, 8, 64);  s += __shfl_xor(s, 4, 64);
        s += __shfl_xor(s, 2, 64);  s += __shfl_xor(s, 1, 64);
        if (t == 0) inv_asum_s = 1.f / (s + 1e-8f);
    }
    __syncthreads();
    if (t < HD_) {
        float a = 0.f;
        for (int l2 = 0; l2 < 64; ++l2)
            a = fmaf(b2f(ctx_s[l2 * CS + t]), alpha_s[l2], a);
        out[(long)b * HD_ + t] = a * inv_asum_s;
    }
}

extern "C" void kernel_launch(void* const* d_in, const int* in_sizes, int n_in,
                              void* d_out, int out_size, void* d_ws, size_t ws_size,
                              hipStream_t stream) {
    const int*   text = (const int*)d_in[0];
    const float* emb  = (const float*)d_in[1];
    const float* WQ   = (const float*)d_in[2];
    const float* bQ   = (const float*)d_in[3];
    const float* WK   = (const float*)d_in[4];
    const float* bK   = (const float*)d_in[5];
    const float* WV   = (const float*)d_in[6];
    const float* bV   = (const float*)d_in[7];
    const float* W1   = (const float*)d_in[8];
    const float* b1   = (const float*)d_in[9];
    const float* W2   = (const float*)d_in[10];
    const float* b2   = (const float*)d_in[11];
    float*       out  = (float*)d_out;

    if (ws_size >= (size_t)WS_FULL) {
        unsigned short* wsp    = (unsigned short*)d_ws;
        unsigned short* ctx_ws = (unsigned short*)((char*)d_ws + CTX_OFF_B);
        const int total_frag_threads = (WQKV_TILES + W1_TILES) * 64;
        pack_weights_new<<<(total_frag_threads + 255) / 256, 256, 0, stream>>>(WQ, WK, WV, W1, wsp);
        te_attn<<<B_, 512, 0, stream>>>(text, emb, bQ, bK, bV, wsp, ctx_ws);
        te_pool<<<B_, 512, 0, stream>>>(ctx_ws, b1, W2, b2, wsp, out);
    } else {
        te_fused_fb<<<B_, 512, 0, stream>>>(text, emb, WQ, bQ, WK, bK, WV, bV,
                                            W1, b1, W2, b2, out);
    }
}